// Round 5
// baseline (424414.502 us; speedup 1.0000x reference)
//
#include <hip/hip_runtime.h>
#include <hip/hip_bf16.h>

#define NEVT 32768
#define NBLK (NEVT / 8)

typedef _Float16 f16;
typedef _Float16 f16x2 __attribute__((ext_vector_type(2)));
typedef float Row128[128];
typedef unsigned int uint32;

#ifndef __has_builtin
#define __has_builtin(x) 0
#endif

__device__ __forceinline__ float dot2f(f16x2 a, f16x2 b, float c) {
#if __has_builtin(__builtin_amdgcn_fdot2)
  return __builtin_amdgcn_fdot2(a, b, c, false);
#else
  return c + (float)a[0] * (float)b[0] + (float)a[1] * (float)b[1];
#endif
}

// ---- fp8 (OCP e4m3fn) decode: 2 fp8 -> 2 f16 ----
__device__ __forceinline__ f16x2 dec2_manual(uint32 two) {
  uint32 b0 = two & 0xff, b1 = (two >> 8) & 0xff;
  uint32 em0 = b0 & 0x7f, em1 = b1 & 0x7f;
  uint32 h0 = ((b0 & 0x80) << 8) | ((em0 < 8) ? 0u : ((em0 << 7) + 0x2000));
  uint32 h1 = ((b1 & 0x80) << 8) | ((em1 < 8) ? 0u : ((em1 << 7) + 0x2000));
  return __builtin_bit_cast(f16x2, (unsigned short)(h0) | (h1 << 16) |
                                   (h0 & 0xffff) ? (h0 | (h1 << 16)) : (h1 << 16));
}
// (simplified correct version below is what we actually use)
__device__ __forceinline__ f16x2 dec2(uint32 two) {
#if __has_builtin(__builtin_amdgcn_cvt_pk_f16_fp8)
  return __builtin_amdgcn_cvt_pk_f16_fp8((short)two);
#else
  uint32 b0 = two & 0xff, b1 = (two >> 8) & 0xff;
  uint32 em0 = b0 & 0x7f, em1 = b1 & 0x7f;
  uint32 h0 = ((b0 & 0x80) << 8) | ((em0 < 8) ? 0u : ((em0 << 7) + 0x2000));
  uint32 h1 = ((b1 & 0x80) << 8) | ((em1 < 8) ? 0u : ((em1 << 7) + 0x2000));
  return __builtin_bit_cast(f16x2, h0 | (h1 << 16));
#endif
}
__device__ __forceinline__ f16x2 cvt8lo(uint32 d) { return dec2(d & 0xffff); }
__device__ __forceinline__ f16x2 cvt8hi(uint32 d) { return dec2(d >> 16); }

// ---- fp8 encode (for wprep) ----
__device__ __forceinline__ uint32 enc_fp8(float f) {
#if __has_builtin(__builtin_amdgcn_cvt_pk_fp8_f32)
  return (uint32)__builtin_amdgcn_cvt_pk_fp8_f32(f, f, 0, false) & 0xff;
#else
  uint32 u = __builtin_bit_cast(uint32, f);
  uint32 s = (u >> 24) & 0x80;
  int E = (int)((u >> 23) & 0xff) - 127 + 7;
  uint32 m = u & 0x7fffff;
  if (E <= 0) return s;
  uint32 keep = m >> 20, rest = m & 0xfffff;
  uint32 rnd = keep + ((rest > 0x80000u) || (rest == 0x80000u && (keep & 1)));
  if (rnd == 8) { rnd = 0; E += 1; }
  if (E >= 16) return s | 0x7e;
  return s | ((uint32)E << 3) | rnd;
#endif
}

__device__ __forceinline__ float lrelu(float v) { return v >= 0.f ? v : 0.2f * v; }

__device__ __forceinline__ float sigmoidf(float x) {
  return 1.f / (1.f + __expf(-x));
}

__device__ __forceinline__ float tanh_f(float x) {
  float ax = fabsf(x);
  float e = __expf(-2.f * ax);
  float t = (1.f - e) / (1.f + e);
  return x >= 0.f ? t : -t;
}

// One residual block on an 8-row tile held in LDS. 128 threads, thread u owns
// output unit u. Two internal barriers.
__device__ __forceinline__ void res_block(Row128* xb, Row128* hb,
    const float* __restrict__ w1, const float* __restrict__ b1,
    const float* __restrict__ w2, const float* __restrict__ b2, int u) {
  float acc[8];
  float bb = b1[u];
  #pragma unroll
  for (int r = 0; r < 8; ++r) acc[r] = bb;
  #pragma unroll 4
  for (int k = 0; k < 128; ++k) {
    float w = w1[u * 128 + k];
    #pragma unroll
    for (int r = 0; r < 8; ++r) acc[r] += w * xb[r][k];
  }
  #pragma unroll
  for (int r = 0; r < 8; ++r) hb[r][u] = lrelu(acc[r]);
  __syncthreads();
  bb = b2[u];
  #pragma unroll
  for (int r = 0; r < 8; ++r) acc[r] = bb;
  #pragma unroll 4
  for (int k = 0; k < 128; ++k) {
    float w = w2[u * 128 + k];
    #pragma unroll
    for (int r = 0; r < 8; ++r) acc[r] += w * hb[r][k];
  }
  #pragma unroll
  for (int r = 0; r < 8; ++r) xb[r][u] = lrelu(xb[r][u] + acc[r]);
  __syncthreads();
}

// ---------------- Encoder stage 1 ----------------
__global__ __launch_bounds__(128) void enc1_kernel(
    const int* __restrict__ atom, const float* __restrict__ tvec,
    const float* __restrict__ mvec, const float* __restrict__ atom_emb,
    const float* __restrict__ mag_w, const float* __restrict__ mag_b,
    const float* __restrict__ pos_w, const float* __restrict__ pos_b,
    const float* __restrict__ reduce_w, const float* __restrict__ reduce_b,
    const float* __restrict__ net_w1, const float* __restrict__ net_b1,
    const float* __restrict__ net_w2, const float* __restrict__ net_b2,
    const float* __restrict__ final_w, const float* __restrict__ final_b,
    float* __restrict__ xf, float* __restrict__ pg) {
  const int u = threadIdx.x;
  const int r0 = blockIdx.x * 8;
  __shared__ float xin[8][384];
  __shared__ float xb[8][128];
  __shared__ float hb[8][128];
  #pragma unroll
  for (int r = 0; r < 8; ++r) {
    int row = r0 + r;
    xin[r][u] = atom_emb[atom[row] * 128 + u];
    xin[r][128 + u] = tvec[row] * pos_w[u] + pos_b[u];
    xin[r][256 + u] = mvec[row] * mag_w[u] + mag_b[u];
  }
  __syncthreads();
  float acc[8];
  float bb = reduce_b[u];
  #pragma unroll
  for (int r = 0; r < 8; ++r) acc[r] = bb;
  #pragma unroll 4
  for (int k = 0; k < 384; ++k) {
    float w = reduce_w[u * 384 + k];
    #pragma unroll
    for (int r = 0; r < 8; ++r) acc[r] += w * xin[r][k];
  }
  #pragma unroll
  for (int r = 0; r < 8; ++r) xb[r][u] = acc[r];
  __syncthreads();
  for (int blk = 0; blk < 4; ++blk)
    res_block(xb, hb, net_w1 + blk * 16384, net_b1 + blk * 128,
              net_w2 + blk * 16384, net_b2 + blk * 128, u);
  bb = final_b[u];
  #pragma unroll
  for (int r = 0; r < 8; ++r) acc[r] = bb;
  #pragma unroll 4
  for (int k = 0; k < 128; ++k) {
    float w = final_w[u * 128 + k];
    #pragma unroll
    for (int r = 0; r < 8; ++r) acc[r] += w * xb[r][k];
  }
  float s = 0.f;
  #pragma unroll
  for (int r = 0; r < 8; ++r) {
    xf[(r0 + r) * 128 + u] = acc[r];
    s += acc[r];
  }
  pg[blockIdx.x * 128 + u] = s;
}

// ---------------- Deterministic column reduction: sum m rows of [128] -------
__global__ __launch_bounds__(1024) void reduce_kernel(
    const float* __restrict__ src, int m, float* __restrict__ dst) {
  int u = threadIdx.x & 127, c = threadIdx.x >> 7;
  float s = 0.f;
  for (int i = c; i < m; i += 8) s += src[i * 128 + u];
  __shared__ float tmp[8][128];
  tmp[c][u] = s;
  __syncthreads();
  if (c == 0) {
    float t = 0.f;
    #pragma unroll
    for (int j = 0; j < 8; ++j) t += tmp[j][u];
    dst[u] = t;
  }
}

// ---------------- Encoder stage 2 ----------------
__global__ __launch_bounds__(128) void enc2_kernel(
    const float* __restrict__ xf, const float* __restrict__ g,
    const float* __restrict__ redg_w, const float* __restrict__ redg_b,
    const float* __restrict__ wg_w1, const float* __restrict__ wg_b1,
    const float* __restrict__ wg_w2, const float* __restrict__ wg_b2,
    const float* __restrict__ gfinal_w, const float* __restrict__ gfinal_b,
    float* __restrict__ pz) {
  const int u = threadIdx.x;
  const int r0 = blockIdx.x * 8;
  __shared__ float xin[8][256];
  __shared__ float xb[8][128];
  __shared__ float hb[8][128];
  #pragma unroll
  for (int r = 0; r < 8; ++r) {
    xin[r][u] = xf[(r0 + r) * 128 + u];
    xin[r][128 + u] = g[u];
  }
  __syncthreads();
  float acc[8];
  float bb = redg_b[u];
  #pragma unroll
  for (int r = 0; r < 8; ++r) acc[r] = bb;
  #pragma unroll 4
  for (int k = 0; k < 256; ++k) {
    float w = redg_w[u * 256 + k];
    #pragma unroll
    for (int r = 0; r < 8; ++r) acc[r] += w * xin[r][k];
  }
  #pragma unroll
  for (int r = 0; r < 8; ++r) xb[r][u] = acc[r];
  __syncthreads();
  for (int blk = 0; blk < 4; ++blk)
    res_block(xb, hb, wg_w1 + blk * 16384, wg_b1 + blk * 128,
              wg_w2 + blk * 16384, wg_b2 + blk * 128, u);
  bb = gfinal_b[u];
  #pragma unroll
  for (int r = 0; r < 8; ++r) acc[r] = bb;
  #pragma unroll 4
  for (int k = 0; k < 128; ++k) {
    float w = gfinal_w[u * 128 + k];
    #pragma unroll
    for (int r = 0; r < 8; ++r) acc[r] += w * xb[r][k];
  }
  float s = 0.f;
  #pragma unroll
  for (int r = 0; r < 8; ++r) s += acc[r];
  pz[blockIdx.x * 128 + u] = s;
}

// -------- Weight pre-conversion: f32 -> f16 copies + fp8(x256) copies -------
#define FP8_SCALE 256.0f
__global__ __launch_bounds__(256) void wprep_kernel(
    const float* __restrict__ wih, const float* __restrict__ whh,
    f16* __restrict__ w16i, f16* __restrict__ w16h,
    unsigned char* __restrict__ w8) {
  int idx = blockIdx.x * 256 + threadIdx.x;
  if (idx < 196608) {
    w16i[idx] = (f16)wih[idx];
    w16h[idx] = (f16)whh[idx];
  }
  if (idx < 49152) {  // pack 4 elems -> 1 dword, both matrices
    uint32 di = 0, dh = 0;
    #pragma unroll
    for (int j = 0; j < 4; ++j) {
      di |= enc_fp8(wih[4 * idx + j] * FP8_SCALE) << (8 * j);
      dh |= enc_fp8(whh[4 * idx + j] * FP8_SCALE) << (8 * j);
    }
    ((uint32*)w8)[idx] = di;
    ((uint32*)w8)[49152 + idx] = dh;
  }
}

// ---------------- Sequential GRU decoder (single workgroup, 512 threads) ----
// R8: fp8-compressed streaming. R4-R7 verdict: register residency beyond
// ~100 compiler-managed dwords/lane is unobtainable (anchors spill; physical
// AGPRs collide with the compiler's own AGPR spill slots -> R7 NaN). The wall
// is the per-CU L2 load path (~102 B/cyc): 786 KB/step = 7700 cyc. So shrink
// the bytes: stream 10 of 12 row-units per thread as fp8 e4m3 (320 KB/step),
// decode in-flight with v_cvt_pk_f16_fp8 into the existing dot2 pipeline.
// B-rows of layers 2,3 stay f16 in LDS (128 KB, R6's known-good pattern).
// Weights pre-scaled x256 at encode (avoids e4m3 subnormals); partial sums
// rescaled x(1/256) at the phase tail. No asm anchors anywhere.

#define SCI (1.f / FP8_SCALE)

// dot a 16-elem fp8 chunk U (uint4) against src f16 chunks Qa (elems 0-7),
// Qb (elems 8-15).
#define D16(U, Qa, Qb, A0, A1) \
  A0 = dot2f(cvt8lo((U).x), __builtin_bit_cast(f16x2, (Qa).x), A0); \
  A1 = dot2f(cvt8hi((U).x), __builtin_bit_cast(f16x2, (Qa).y), A1); \
  A0 = dot2f(cvt8lo((U).y), __builtin_bit_cast(f16x2, (Qa).z), A0); \
  A1 = dot2f(cvt8hi((U).y), __builtin_bit_cast(f16x2, (Qa).w), A1); \
  A0 = dot2f(cvt8lo((U).z), __builtin_bit_cast(f16x2, (Qb).x), A0); \
  A1 = dot2f(cvt8hi((U).z), __builtin_bit_cast(f16x2, (Qb).y), A1); \
  A0 = dot2f(cvt8lo((U).w), __builtin_bit_cast(f16x2, (Qb).z), A0); \
  A1 = dot2f(cvt8hi((U).w), __builtin_bit_cast(f16x2, (Qb).w), A1);

// f16 LDS chunk (float4 W = 8 f16) against src float4 Q.
#define D8L(W, Q, A0, A1) \
  A0 = dot2f(__builtin_bit_cast(f16x2,(W).x), __builtin_bit_cast(f16x2,(Q).x), A0); \
  A1 = dot2f(__builtin_bit_cast(f16x2,(W).y), __builtin_bit_cast(f16x2,(Q).y), A1); \
  A0 = dot2f(__builtin_bit_cast(f16x2,(W).z), __builtin_bit_cast(f16x2,(Q).z), A0); \
  A1 = dot2f(__builtin_bit_cast(f16x2,(W).w), __builtin_bit_cast(f16x2,(Q).w), A1);

// Phase src staging: 8 float4 (=64 f16) broadcast reads from srcbuf.
#define PH_HEAD(L) \
  const float4* s4_ = (const float4*)(srcf + soff_base + (L) * sideOff); \
  float4 q0_=s4_[0],q1_=s4_[1],q2_=s4_[2],q3_=s4_[3]; \
  float4 q4_=s4_[4],q5_=s4_[5],q6_=s4_[6],q7_=s4_[7]; \
  float aA0_=0.f,aA1_=0.f,aB0_=0.f,aB1_=0.f,aC0_=0.f,aC1_=0.f;

// Layers 0,1: A, B, C all fp8-streamed.
#define PH_S(L) do { \
  const uint4* wa_ = (const uint4*)(w8 + wAb_ + (L) * 49152); \
  const uint4* wb_ = (const uint4*)(w8 + wAb_ + (L) * 49152 + 128); \
  const uint4* wc_ = (const uint4*)(w8 + wAb_ + (L) * 49152 + 256); \
  uint4 ua0=wa_[0],ua1=wa_[1],ua2=wa_[2],ua3=wa_[3]; \
  uint4 ub0=wb_[0],ub1=wb_[1],ub2=wb_[2],ub3=wb_[3]; \
  uint4 uc0=wc_[0],uc1=wc_[1],uc2=wc_[2],uc3=wc_[3]; \
  PH_HEAD(L) \
  D16(ua0,q0_,q1_,aA0_,aA1_) D16(ua1,q2_,q3_,aA0_,aA1_) \
  D16(ua2,q4_,q5_,aA0_,aA1_) D16(ua3,q6_,q7_,aA0_,aA1_) \
  D16(ub0,q0_,q1_,aB0_,aB1_) D16(ub1,q2_,q3_,aB0_,aB1_) \
  D16(ub2,q4_,q5_,aB0_,aB1_) D16(ub3,q6_,q7_,aB0_,aB1_) \
  D16(uc0,q0_,q1_,aC0_,aC1_) D16(uc1,q2_,q3_,aC0_,aC1_) \
  D16(uc2,q4_,q5_,aC0_,aC1_) D16(uc3,q6_,q7_,aC0_,aC1_) \
  pgf[d0]     = (aA0_ + aA1_) * SCI; \
  pgf[d0 + 2] = (aB0_ + aB1_) * SCI; \
  pgf[d0 + 4] = (aC0_ + aC1_) * SCI; \
} while (0)

// Layers 2,3: A, C fp8-streamed; B from LDS f16 (unscaled).
#define PH_LB(L, WL) do { \
  const uint4* wa_ = (const uint4*)(w8 + wAb_ + (L) * 49152); \
  const uint4* wc_ = (const uint4*)(w8 + wAb_ + (L) * 49152 + 256); \
  uint4 ua0=wa_[0],ua1=wa_[1],ua2=wa_[2],ua3=wa_[3]; \
  uint4 uc0=wc_[0],uc1=wc_[1],uc2=wc_[2],uc3=wc_[3]; \
  PH_HEAD(L) \
  D16(ua0,q0_,q1_,aA0_,aA1_) D16(ua1,q2_,q3_,aA0_,aA1_) \
  D16(ua2,q4_,q5_,aA0_,aA1_) D16(ua3,q6_,q7_,aA0_,aA1_) \
  { float4 w_; \
    w_=(WL)[0*512+tid]; D8L(w_,q0_,aB0_,aB1_) \
    w_=(WL)[1*512+tid]; D8L(w_,q1_,aB0_,aB1_) \
    w_=(WL)[2*512+tid]; D8L(w_,q2_,aB0_,aB1_) \
    w_=(WL)[3*512+tid]; D8L(w_,q3_,aB0_,aB1_) \
    w_=(WL)[4*512+tid]; D8L(w_,q4_,aB0_,aB1_) \
    w_=(WL)[5*512+tid]; D8L(w_,q5_,aB0_,aB1_) \
    w_=(WL)[6*512+tid]; D8L(w_,q6_,aB0_,aB1_) \
    w_=(WL)[7*512+tid]; D8L(w_,q7_,aB0_,aB1_) } \
  D16(uc0,q0_,q1_,aC0_,aC1_) D16(uc1,q2_,q3_,aC0_,aC1_) \
  D16(uc2,q4_,q5_,aC0_,aC1_) D16(uc3,q6_,q7_,aC0_,aC1_) \
  pgf[d0]     = (aA0_ + aA1_) * SCI; \
  pgf[d0 + 2] = (aB0_ + aB1_); \
  pgf[d0 + 4] = (aC0_ + aC1_) * SCI; \
} while (0)

#define GATE(L, T) \
  if (tid < 128) { \
    const float2* gi2_ = (const float2*)pgf; \
    const float2* gh2_ = (const float2*)(pgf + 768); \
    float2 ar_ = gi2_[tid],      br_ = gh2_[tid]; \
    float2 az_ = gi2_[128+tid],  bz_ = gh2_[128+tid]; \
    float2 an_ = gi2_[256+tid],  bn_ = gh2_[256+tid]; \
    float r_ = sigmoidf((ar_.x + ar_.y) + (br_.x + br_.y) + bsum_r[L][tid]); \
    float z_ = sigmoidf((az_.x + az_.y) + (bz_.x + bz_.y) + bsum_z[L][tid]); \
    float n_ = tanh_f((an_.x + an_.y) + b_in[L][tid] + \
                      r_ * ((bn_.x + bn_.y) + b_hn[L][tid])); \
    float h_ = (1.f - z_) * n_ + z_ * h32[L][tid]; \
    h32[L][tid] = h_; f16 hh_ = (f16)h_; \
    srcbuf[(1 + (L)) * 128 + tid] = hh_; srcbuf[tid] = hh_; \
    if ((L) == 3) enc[(size_t)(T) * 128 + tid] = h_; \
  }

__global__ __attribute__((amdgpu_flat_work_group_size(512, 512)))
__attribute__((amdgpu_waves_per_eu(2, 2))) void gru_kernel(
    const f16* __restrict__ w16, const unsigned char* __restrict__ w8,
    const float* __restrict__ bih, const float* __restrict__ bhh,
    const float* __restrict__ zvec, float* __restrict__ enc) {
  const int tid = threadIdx.x;

  __shared__ __align__(16) float4 wldsB2[4096];       // 64 KB: B-rows layer 2
  __shared__ __align__(16) float4 wldsB3[4096];       // 64 KB: B-rows layer 3
  __shared__ __align__(16) float pgbuf[1536];         // 6 KB
  __shared__ __align__(16) f16 srcbuf[640];           // 1.25 KB
  __shared__ __align__(16) float h32[4][128];         // 2 KB
  __shared__ __align__(16) float cur32[128];          // 0.5 KB
  __shared__ float bsum_r[4][128], bsum_z[4][128];    // 4 KB
  __shared__ float b_in[4][128], b_hn[4][128];        // 4 KB

  float* const pgf = pgbuf;
  const f16* const srcf = srcbuf;

  // Row-grouped unit mapping (validated in R6).
  const int side = tid >> 8;           // 0 = gi (W_ih), 1 = gh (W_hh)
  const int ti = tid & 255;
  const int half = ti & 1;
  const int hs = half * 64;
  const int rb = 3 * (ti >> 1);        // rows rb, rb+1, rb+2 of [0,384)
  const int d0 = side * 768 + rb * 2 + half;
  const int soff_base = side ? (128 + hs) : hs;
  const int sideOff = side * 128;
  const int wAb_ = side * 196608 + rb * 128 + hs;  // A-row elem base, layer 0

  // LDS-resident weights: B-rows layers 2,3 (f16). [chunk][tid] so a wave's
  // ds_read_b128 is lane-contiguous (conflict-free).
  {
    const float4* p2 = (const float4*)(w16 + wAb_ + 2 * 49152 + 128);
    const float4* p3 = (const float4*)(w16 + wAb_ + 3 * 49152 + 128);
    #pragma unroll
    for (int c = 0; c < 8; ++c) {
      wldsB2[c * 512 + tid] = p2[c];
      wldsB3[c * 512 + tid] = p3[c];
    }
  }

  if (tid < 128) {
    cur32[tid] = zvec[tid];
    srcbuf[tid] = (f16)0.f;
    #pragma unroll
    for (int l = 0; l < 4; ++l) {
      h32[l][tid] = 0.f;
      srcbuf[(1 + l) * 128 + tid] = (f16)0.f;
    }
  }
  {
    int l_ = tid >> 7, row_ = tid & 127;
    bsum_r[l_][row_] = bih[l_*384 + row_]       + bhh[l_*384 + row_];
    bsum_z[l_][row_] = bih[l_*384 + 128 + row_] + bhh[l_*384 + 128 + row_];
    b_in[l_][row_]   = bih[l_*384 + 256 + row_];
    b_hn[l_][row_]   = bhh[l_*384 + 256 + row_];
  }
  __syncthreads();

  // ---- peeled step t = 0: layer-0 gi in f32 (z ~1e7 overflows f16) ----
  {
    if (tid < 256) {  // side == 0: f32 path against decoded fp8 rows
      const float* xs_ = cur32 + hs;
      #pragma unroll
      for (int rr = 0; rr < 3; ++rr) {
        const uint32* wp_ = (const uint32*)(w8 + wAb_ + rr * 128);
        float a0_ = 0.f, a1_ = 0.f;
        #pragma unroll
        for (int k = 0; k < 16; ++k) {
          uint32 d_ = wp_[k];
          f16x2 lo_ = cvt8lo(d_), hi_ = cvt8hi(d_);
          a0_ += (float)lo_[0] * xs_[4*k]     + (float)hi_[0] * xs_[4*k + 2];
          a1_ += (float)lo_[1] * xs_[4*k + 1] + (float)hi_[1] * xs_[4*k + 3];
        }
        pgf[d0 + 2 * rr] = (a0_ + a1_) * SCI;
      }
    } else {          // side == 1: h16 == 0 -> normal path yields zeros
      PH_S(0);
    }
    __syncthreads();
    GATE(0, 0)
    __syncthreads();
    PH_S(1);
    __syncthreads();
    GATE(1, 0)
    __syncthreads();
    PH_LB(2, wldsB2);
    __syncthreads();
    GATE(2, 0)
    __syncthreads();
    PH_LB(3, wldsB3);
    __syncthreads();
    GATE(3, 0)
    __syncthreads();
  }

  #pragma unroll 1
  for (int t = 1; t < NEVT; ++t) {
    PH_S(0);
    __syncthreads();
    GATE(0, t)
    __syncthreads();
    PH_S(1);
    __syncthreads();
    GATE(1, t)
    __syncthreads();
    PH_LB(2, wldsB2);
    __syncthreads();
    GATE(2, t)
    __syncthreads();
    PH_LB(3, wldsB3);
    __syncthreads();
    GATE(3, t)
    __syncthreads();
  }
}

// ---------------- Output heads ----------------
__global__ __launch_bounds__(128) void heads_kernel(
    const float* __restrict__ enc,
    const float* __restrict__ ah_w1, const float* __restrict__ ah_b1,
    const float* __restrict__ ah_w2, const float* __restrict__ ah_b2,
    const float* __restrict__ ah_w, const float* __restrict__ ah_b,
    const float* __restrict__ ph_w1, const float* __restrict__ ph_b1,
    const float* __restrict__ ph_w2, const float* __restrict__ ph_b2,
    const float* __restrict__ ph_w, const float* __restrict__ ph_b,
    const float* __restrict__ mh_w1, const float* __restrict__ mh_b1,
    const float* __restrict__ mh_w2, const float* __restrict__ mh_b2,
    const float* __restrict__ mh_w, const float* __restrict__ mh_b,
    float* __restrict__ oa, float* __restrict__ op, float* __restrict__ om) {
  const int u = threadIdx.x;
  const int r0 = blockIdx.x * 8;
  __shared__ float eb[8][128], xb[8][128], hb[8][128];
  #pragma unroll
  for (int r = 0; r < 8; ++r) eb[r][u] = enc[(size_t)(r0 + r) * 128 + u];
  // ---- atoms head ----
  #pragma unroll
  for (int r = 0; r < 8; ++r) xb[r][u] = eb[r][u];
  __syncthreads();
  for (int blk = 0; blk < 2; ++blk)
    res_block(xb, hb, ah_w1 + blk * 16384, ah_b1 + blk * 128,
              ah_w2 + blk * 16384, ah_b2 + blk * 128, u);
  {
    float acc[8];
    float bb = ah_b[u];
    #pragma unroll
    for (int r = 0; r < 8; ++r) acc[r] = bb;
    #pragma unroll 4
    for (int k = 0; k < 128; ++k) {
      float w = ah_w[u * 128 + k];
      #pragma unroll
      for (int r = 0; r < 8; ++r) acc[r] += w * xb[r][k];
    }
    #pragma unroll
    for (int r = 0; r < 8; ++r) oa[(size_t)(r0 + r) * 128 + u] = acc[r];
  }
  __syncthreads();
  // ---- pos head ----
  #pragma unroll
  for (int r = 0; r < 8; ++r) xb[r][u] = eb[r][u];
  __syncthreads();
  for (int blk = 0; blk < 2; ++blk)
    res_block(xb, hb, ph_w1 + blk * 16384, ph_b1 + blk * 128,
              ph_w2 + blk * 16384, ph_b2 + blk * 128, u);
  if (u < 8) {
    int r = u;
    float s = ph_b[0];
    for (int k = 0; k < 128; ++k) s += ph_w[k] * xb[r][k];
    s = s < 0.f ? 0.f : (s > 1.f ? 1.f : s);
    op[r0 + r] = s;
  }
  __syncthreads();
  // ---- mags head ----
  #pragma unroll
  for (int r = 0; r < 8; ++r) xb[r][u] = eb[r][u];
  __syncthreads();
  for (int blk = 0; blk < 2; ++blk)
    res_block(xb, hb, mh_w1 + blk * 16384, mh_b1 + blk * 128,
              mh_w2 + blk * 16384, mh_b2 + blk * 128, u);
  if (u < 8) {
    int r = u;
    float s = mh_b[0];
    for (int k = 0; k < 128; ++k) s += mh_w[k] * xb[r][k];
    om[r0 + r] = s;
  }
}

extern "C" void kernel_launch(void* const* d_in, const int* in_sizes, int n_in,
                              void* d_out, int out_size, void* d_ws, size_t ws_size,
                              hipStream_t stream) {
  const int* atom = (const int*)d_in[0];
  const float* tvec = (const float*)d_in[1];
  const float* mvec = (const float*)d_in[2];
  const float* atom_emb = (const float*)d_in[3];
  const float* mag_w = (const float*)d_in[4];
  const float* mag_b = (const float*)d_in[5];
  const float* pos_w = (const float*)d_in[6];
  const float* pos_b = (const float*)d_in[7];
  const float* reduce_w = (const float*)d_in[8];
  const float* reduce_b = (const float*)d_in[9];
  const float* net_w1 = (const float*)d_in[10];
  const float* net_b1 = (const float*)d_in[11];
  const float* net_w2 = (const float*)d_in[12];
  const float* net_b2 = (const float*)d_in[13];
  const float* final_w = (const float*)d_in[14];
  const float* final_b = (const float*)d_in[15];
  const float* redg_w = (const float*)d_in[16];
  const float* redg_b = (const float*)d_in[17];
  const float* wg_w1 = (const float*)d_in[18];
  const float* wg_b1 = (const float*)d_in[19];
  const float* wg_w2 = (const float*)d_in[20];
  const float* wg_b2 = (const float*)d_in[21];
  const float* gfinal_w = (const float*)d_in[22];
  const float* gfinal_b = (const float*)d_in[23];
  const float* gru_wih = (const float*)d_in[24];
  const float* gru_whh = (const float*)d_in[25];
  const float* gru_bih = (const float*)d_in[26];
  const float* gru_bhh = (const float*)d_in[27];
  const float* ah_w1 = (const float*)d_in[28];
  const float* ah_b1 = (const float*)d_in[29];
  const float* ah_w2 = (const float*)d_in[30];
  const float* ah_b2 = (const float*)d_in[31];
  const float* ah_w = (const float*)d_in[32];
  const float* ah_b = (const float*)d_in[33];
  const float* ph_w1 = (const float*)d_in[34];
  const float* ph_b1 = (const float*)d_in[35];
  const float* ph_w2 = (const float*)d_in[36];
  const float* ph_b2 = (const float*)d_in[37];
  const float* ph_w = (const float*)d_in[38];
  const float* ph_b = (const float*)d_in[39];
  const float* mh_w1 = (const float*)d_in[40];
  const float* mh_b1 = (const float*)d_in[41];
  const float* mh_w2 = (const float*)d_in[42];
  const float* mh_b2 = (const float*)d_in[43];
  const float* mh_w = (const float*)d_in[44];
  const float* mh_b = (const float*)d_in[45];

  float* out = (float*)d_out;
  float* oa = out;                        // atoms [N,128]
  float* op = out + (size_t)NEVT * 128;   // pos [N]
  float* om = op + NEVT;                  // mags [N]
  float* oz = om + NEVT;                  // z [128]

  float* enc = (float*)d_ws;              // encodings [N,128] : 16 MB
  float* pg = enc + (size_t)NEVT * 128;   // stage-1 partials: 2 MB (reused for w16/w8)
  float* pz = pg + (size_t)NBLK * 128;    // stage-2 partials: 2 MB
  float* gv = pz + (size_t)NBLK * 128;    // g [128]
  float* xf = oa;  // stage-1 output staged in atoms region; heads overwrite later

  // Weight copies overlay the pg region once pg has been reduced into gv:
  // f16 matrices (768 KB) then fp8 matrices (384 KB).
  f16* w16i = (f16*)pg;                        // 384 KB
  f16* w16h = w16i + 196608;                   // 384 KB (contiguous)
  unsigned char* w8 = (unsigned char*)(w16i + 2 * 196608);  // 384 KB fp8

  enc1_kernel<<<NBLK, 128, 0, stream>>>(atom, tvec, mvec, atom_emb, mag_w, mag_b,
      pos_w, pos_b, reduce_w, reduce_b, net_w1, net_b1, net_w2, net_b2,
      final_w, final_b, xf, pg);
  reduce_kernel<<<1, 1024, 0, stream>>>(pg, NBLK, gv);
  wprep_kernel<<<768, 256, 0, stream>>>(gru_wih, gru_whh, w16i, w16h, w8);
  enc2_kernel<<<NBLK, 128, 0, stream>>>(xf, gv, redg_w, redg_b, wg_w1, wg_b1,
      wg_w2, wg_b2, gfinal_w, gfinal_b, pz);
  reduce_kernel<<<1, 1024, 0, stream>>>(pz, NBLK, oz);
  gru_kernel<<<1, 512, 0, stream>>>(w16i, w8, gru_bih, gru_bhh, oz, enc);
  heads_kernel<<<NBLK, 128, 0, stream>>>(enc, ah_w1, ah_b1, ah_w2, ah_b2, ah_w, ah_b,
      ph_w1, ph_b1, ph_w2, ph_b2, ph_w, ph_b, mh_w1, mh_b1, mh_w2, mh_b2, mh_w, mh_b,
      oa, op, om);
}

// Round 6
// 320104.663 us; speedup vs baseline: 1.3259x; 1.3259x over previous
//
#include <hip/hip_runtime.h>
#include <hip/hip_bf16.h>

#define NEVT 32768
#define NBLK (NEVT / 8)

typedef _Float16 f16;
typedef _Float16 f16x2 __attribute__((ext_vector_type(2)));
typedef float Row128[128];
typedef unsigned long long u64;

#ifndef __has_builtin
#define __has_builtin(x) 0
#endif

__device__ __forceinline__ float dot2f(f16x2 a, f16x2 b, float c) {
#if __has_builtin(__builtin_amdgcn_fdot2)
  return __builtin_amdgcn_fdot2(a, b, c, false);
#else
  return c + (float)a[0] * (float)b[0] + (float)a[1] * (float)b[1];
#endif
}

__device__ __forceinline__ float lrelu(float v) { return v >= 0.f ? v : 0.2f * v; }

__device__ __forceinline__ float sigmoidf(float x) {
  return 1.f / (1.f + __expf(-x));
}

__device__ __forceinline__ float tanh_f(float x) {
  float ax = fabsf(x);
  float e = __expf(-2.f * ax);
  float t = (1.f - e) / (1.f + e);
  return x >= 0.f ? t : -t;
}

// ---- cross-CU relaxed agent-scope atomics (sc1: bypass L1/L2, no inv) ----
__device__ __forceinline__ u64 ld_rlx_u64(const u64* p) {
  return __hip_atomic_load(p, __ATOMIC_RELAXED, __HIP_MEMORY_SCOPE_AGENT);
}
__device__ __forceinline__ void st_rlx_u64(u64* p, u64 v) {
  __hip_atomic_store(p, v, __ATOMIC_RELAXED, __HIP_MEMORY_SCOPE_AGENT);
}
__device__ __forceinline__ u64 pk(float v, int tag) {
  return (u64)__float_as_uint(v) | ((u64)(unsigned)tag << 32);
}
#define SPIN_CAP (1L << 28)

// One residual block on an 8-row tile held in LDS. 128 threads, thread u owns
// output unit u. Two internal barriers.
__device__ __forceinline__ void res_block(Row128* xb, Row128* hb,
    const float* __restrict__ w1, const float* __restrict__ b1,
    const float* __restrict__ w2, const float* __restrict__ b2, int u) {
  float acc[8];
  float bb = b1[u];
  #pragma unroll
  for (int r = 0; r < 8; ++r) acc[r] = bb;
  #pragma unroll 4
  for (int k = 0; k < 128; ++k) {
    float w = w1[u * 128 + k];
    #pragma unroll
    for (int r = 0; r < 8; ++r) acc[r] += w * xb[r][k];
  }
  #pragma unroll
  for (int r = 0; r < 8; ++r) hb[r][u] = lrelu(acc[r]);
  __syncthreads();
  bb = b2[u];
  #pragma unroll
  for (int r = 0; r < 8; ++r) acc[r] = bb;
  #pragma unroll 4
  for (int k = 0; k < 128; ++k) {
    float w = w2[u * 128 + k];
    #pragma unroll
    for (int r = 0; r < 8; ++r) acc[r] += w * hb[r][k];
  }
  #pragma unroll
  for (int r = 0; r < 8; ++r) xb[r][u] = lrelu(xb[r][u] + acc[r]);
  __syncthreads();
}

// ---------------- Encoder stage 1 ----------------
__global__ __launch_bounds__(128) void enc1_kernel(
    const int* __restrict__ atom, const float* __restrict__ tvec,
    const float* __restrict__ mvec, const float* __restrict__ atom_emb,
    const float* __restrict__ mag_w, const float* __restrict__ mag_b,
    const float* __restrict__ pos_w, const float* __restrict__ pos_b,
    const float* __restrict__ reduce_w, const float* __restrict__ reduce_b,
    const float* __restrict__ net_w1, const float* __restrict__ net_b1,
    const float* __restrict__ net_w2, const float* __restrict__ net_b2,
    const float* __restrict__ final_w, const float* __restrict__ final_b,
    float* __restrict__ xf, float* __restrict__ pg) {
  const int u = threadIdx.x;
  const int r0 = blockIdx.x * 8;
  __shared__ float xin[8][384];
  __shared__ float xb[8][128];
  __shared__ float hb[8][128];
  #pragma unroll
  for (int r = 0; r < 8; ++r) {
    int row = r0 + r;
    xin[r][u] = atom_emb[atom[row] * 128 + u];
    xin[r][128 + u] = tvec[row] * pos_w[u] + pos_b[u];
    xin[r][256 + u] = mvec[row] * mag_w[u] + mag_b[u];
  }
  __syncthreads();
  float acc[8];
  float bb = reduce_b[u];
  #pragma unroll
  for (int r = 0; r < 8; ++r) acc[r] = bb;
  #pragma unroll 4
  for (int k = 0; k < 384; ++k) {
    float w = reduce_w[u * 384 + k];
    #pragma unroll
    for (int r = 0; r < 8; ++r) acc[r] += w * xin[r][k];
  }
  #pragma unroll
  for (int r = 0; r < 8; ++r) xb[r][u] = acc[r];
  __syncthreads();
  for (int blk = 0; blk < 4; ++blk)
    res_block(xb, hb, net_w1 + blk * 16384, net_b1 + blk * 128,
              net_w2 + blk * 16384, net_b2 + blk * 128, u);
  bb = final_b[u];
  #pragma unroll
  for (int r = 0; r < 8; ++r) acc[r] = bb;
  #pragma unroll 4
  for (int k = 0; k < 128; ++k) {
    float w = final_w[u * 128 + k];
    #pragma unroll
    for (int r = 0; r < 8; ++r) acc[r] += w * xb[r][k];
  }
  float s = 0.f;
  #pragma unroll
  for (int r = 0; r < 8; ++r) {
    xf[(r0 + r) * 128 + u] = acc[r];
    s += acc[r];
  }
  pg[blockIdx.x * 128 + u] = s;
}

// ---------------- Deterministic column reduction: sum m rows of [128] -------
__global__ __launch_bounds__(1024) void reduce_kernel(
    const float* __restrict__ src, int m, float* __restrict__ dst) {
  int u = threadIdx.x & 127, c = threadIdx.x >> 7;
  float s = 0.f;
  for (int i = c; i < m; i += 8) s += src[i * 128 + u];
  __shared__ float tmp[8][128];
  tmp[c][u] = s;
  __syncthreads();
  if (c == 0) {
    float t = 0.f;
    #pragma unroll
    for (int j = 0; j < 8; ++j) t += tmp[j][u];
    dst[u] = t;
  }
}

// ---------------- Encoder stage 2 ----------------
__global__ __launch_bounds__(128) void enc2_kernel(
    const float* __restrict__ xf, const float* __restrict__ g,
    const float* __restrict__ redg_w, const float* __restrict__ redg_b,
    const float* __restrict__ wg_w1, const float* __restrict__ wg_b1,
    const float* __restrict__ wg_w2, const float* __restrict__ wg_b2,
    const float* __restrict__ gfinal_w, const float* __restrict__ gfinal_b,
    float* __restrict__ pz) {
  const int u = threadIdx.x;
  const int r0 = blockIdx.x * 8;
  __shared__ float xin[8][256];
  __shared__ float xb[8][128];
  __shared__ float hb[8][128];
  #pragma unroll
  for (int r = 0; r < 8; ++r) {
    xin[r][u] = xf[(r0 + r) * 128 + u];
    xin[r][128 + u] = g[u];
  }
  __syncthreads();
  float acc[8];
  float bb = redg_b[u];
  #pragma unroll
  for (int r = 0; r < 8; ++r) acc[r] = bb;
  #pragma unroll 4
  for (int k = 0; k < 256; ++k) {
    float w = redg_w[u * 256 + k];
    #pragma unroll
    for (int r = 0; r < 8; ++r) acc[r] += w * xin[r][k];
  }
  #pragma unroll
  for (int r = 0; r < 8; ++r) xb[r][u] = acc[r];
  __syncthreads();
  for (int blk = 0; blk < 4; ++blk)
    res_block(xb, hb, wg_w1 + blk * 16384, wg_b1 + blk * 128,
              wg_w2 + blk * 16384, wg_b2 + blk * 128, u);
  bb = gfinal_b[u];
  #pragma unroll
  for (int r = 0; r < 8; ++r) acc[r] = bb;
  #pragma unroll 4
  for (int k = 0; k < 128; ++k) {
    float w = gfinal_w[u * 128 + k];
    #pragma unroll
    for (int r = 0; r < 8; ++r) acc[r] += w * xb[r][k];
  }
  float s = 0.f;
  #pragma unroll
  for (int r = 0; r < 8; ++r) s += acc[r];
  pz[blockIdx.x * 128 + u] = s;
}

// -------- Weight pre-conversion f32 -> f16 + comm-buffer init --------
__global__ __launch_bounds__(256) void wprep_kernel(
    const float* __restrict__ wih, const float* __restrict__ whh,
    f16* __restrict__ w16i, f16* __restrict__ w16h,
    u64* __restrict__ hb2, u64* __restrict__ ghb2) {
  int idx = blockIdx.x * 256 + threadIdx.x;
  if (idx < 196608) {
    w16i[idx] = (f16)wih[idx];
    w16h[idx] = (f16)whh[idx];
  }
  if (blockIdx.x == 0) {
    // tags: hb2 = -1 (nothing published), ghb2 = 0 (step-0 zeros valid)
    for (int i = threadIdx.x; i < 512; i += 256) hb2[i] = pk(0.f, -1);
    for (int i = threadIdx.x; i < 1536; i += 256) ghb2[i] = pk(0.f, 0);
  }
}

// ---------------- GRU decoder: 2 cooperating workgroups on 2 CUs ------------
// R9: the only axis left is MORE CUs. R0/R6: one CU's load path pins the step
// at 786 KB / ~102 B/cyc = 7700 cyc. R4-R7: >~100 dw/lane registers are
// unobtainable. R8: in-flight fp8 decode = VALU/latency disaster. So split
// the step across two CUs: block 0 (gi) owns W_ih + gates + h (the critical
// path); block 1 (gh) owns W_hh. Key slack: gh_l(t) depends only on
// h_l(t-1), so gh runs ~1 phase behind gi and its results arrive ~3 phases
// before gi needs them. Each CU holds 144 KB of its matrix in LDS (units
// 480..767 of each layer) and streams only 60 KB/phase (240 KB/step) from L2.
// Cross-CU data uses RELAXED agent-scope atomics only (sc1, cache-bypassing;
// acquire/release would invalidate the per-XCD L2 and evict the streamed
// weights every phase). Every communicated float is a self-validating 8-byte
// word (step_tag<<32 | value): one 64-bit load = datum + freshness proof.
// Single-buffering is overrun-free: gi can't publish h_l(t) before gh
// consumed h_l(t-1) (gi's gate_l(t) needs ghb tags >= t, which gh only
// publishes after consuming h_l(t-1)), and symmetrically for gh.

#define BC(x) __builtin_bit_cast(f16x2, (x))
#define D8L(W, Q) \
  a0 = dot2f(BC((W).x), BC((Q).x), a0); a1 = dot2f(BC((W).y), BC((Q).y), a1); \
  a0 = dot2f(BC((W).z), BC((Q).z), a0); a1 = dot2f(BC((W).w), BC((Q).w), a1);

// Streamed-weight preload (units 0..479): issued first so the L2 latency
// hides under the spin/LDS work that follows.
#define WLOAD(l) \
  float4 w0, w1, w2, w3, w4, w5, w6, w7; \
  if (tid < 480) { \
    const float4* gp_ = (const float4*)(wside + (size_t)(l) * 49152 + tid * 64); \
    w0 = gp_[0]; w1 = gp_[1]; w2 = gp_[2]; w3 = gp_[3]; \
    w4 = gp_[4]; w5 = gp_[5]; w6 = gp_[6]; w7 = gp_[7]; \
  }

// Per-phase dots: unit uA = tid (streamed if tid<480 else LDS), unit
// uB = tid+256 (tid>=256 only; always LDS-resident). Both share the same
// 64-f16 src half (tid&1; uB parity equals uA parity since 256 is even).
#define DOTS(l) { \
  const float4* s4_ = ((const float4*)sxbuf) + (tid & 1) * 8; \
  float4 q0 = s4_[0], q1 = s4_[1], q2 = s4_[2], q3 = s4_[3]; \
  float4 q4 = s4_[4], q5 = s4_[5], q6 = s4_[6], q7 = s4_[7]; \
  float accA; \
  { float a0 = 0.f, a1 = 0.f; \
    if (tid < 480) { \
      D8L(w0, q0) D8L(w1, q1) D8L(w2, q2) D8L(w3, q3) \
      D8L(w4, q4) D8L(w5, q5) D8L(w6, q6) D8L(w7, q7) \
    } else { \
      int b_ = (l) * 2304 + (tid - 480); float4 w_; \
      w_ = wl[b_];        D8L(w_, q0) w_ = wl[b_ + 288];  D8L(w_, q1) \
      w_ = wl[b_ + 576];  D8L(w_, q2) w_ = wl[b_ + 864];  D8L(w_, q3) \
      w_ = wl[b_ + 1152]; D8L(w_, q4) w_ = wl[b_ + 1440]; D8L(w_, q5) \
      w_ = wl[b_ + 1728]; D8L(w_, q6) w_ = wl[b_ + 2016]; D8L(w_, q7) \
    } \
    accA = a0 + a1; } \
  pg[tid] = accA; \
  if (tid >= 256) { \
    float a0 = 0.f, a1 = 0.f; \
    int b_ = (l) * 2304 + (tid - 224); float4 w_; \
    w_ = wl[b_];        D8L(w_, q0) w_ = wl[b_ + 288];  D8L(w_, q1) \
    w_ = wl[b_ + 576];  D8L(w_, q2) w_ = wl[b_ + 864];  D8L(w_, q3) \
    w_ = wl[b_ + 1152]; D8L(w_, q4) w_ = wl[b_ + 1440]; D8L(w_, q5) \
    w_ = wl[b_ + 1728]; D8L(w_, q6) w_ = wl[b_ + 2016]; D8L(w_, q7) \
    pg[tid + 256] = a0 + a1; \
  } }

// gi: fetch gh row-sums for (l, t) — three tagged words, loads issued
// together (one L3 round trip in steady state).
#define GH_FETCH(l, t) \
  float ghr = 0.f, ghz = 0.f, ghn = 0.f; \
  if (tid < 128) { \
    u64 x1_, x2_, x3_; long gd_ = 0; \
    do { \
      x1_ = ld_rlx_u64(ghb2 + (l) * 384 + tid); \
      x2_ = ld_rlx_u64(ghb2 + (l) * 384 + 128 + tid); \
      x3_ = ld_rlx_u64(ghb2 + (l) * 384 + 256 + tid); \
    } while (((int)(x1_ >> 32) < (t) || (int)(x2_ >> 32) < (t) || \
              (int)(x3_ >> 32) < (t)) && ++gd_ < SPIN_CAP); \
    ghr = __uint_as_float((unsigned)x1_); \
    ghz = __uint_as_float((unsigned)x2_); \
    ghn = __uint_as_float((unsigned)x3_); \
  }

#define GI_GATE(l, t) \
  if (tid < 128) { \
    float gir = pg[2 * tid] + pg[2 * tid + 1]; \
    float giz = pg[256 + 2 * tid] + pg[257 + 2 * tid]; \
    float gin = pg[512 + 2 * tid] + pg[513 + 2 * tid]; \
    float r_ = sigmoidf(gir + ghr + bs_r[l]); \
    float z_ = sigmoidf(giz + ghz + bs_z[l]); \
    float n_ = tanh_f(gin + bi_n[l] + r_ * (ghn + bh_n[l])); \
    float h_ = (1.f - z_) * n_ + z_ * h32[l][tid]; \
    h32[l][tid] = h_; \
    sxbuf[tid] = (f16)h_; \
    st_rlx_u64(hb2 + (l) * 128 + tid, pk(h_, (t))); \
    if ((l) == 3) enc[(size_t)(t) * 128 + tid] = h_; \
  }

#define GI_PHASE(l, t) { \
  WLOAD(l) \
  GH_FETCH(l, t) \
  DOTS(l) \
  __syncthreads(); \
  GI_GATE(l, t) \
  __syncthreads(); \
}

#define GH_PHASE(l, t) { \
  WLOAD(l) \
  if (tid < 128) { \
    u64 x_; long gd_ = 0; \
    do { x_ = ld_rlx_u64(hb2 + (l) * 128 + tid); } \
    while ((int)(x_ >> 32) < (t) - 1 && ++gd_ < SPIN_CAP); \
    sxbuf[tid] = (f16)__uint_as_float((unsigned)x_); \
  } \
  __syncthreads(); \
  DOTS(l) \
  __syncthreads(); \
  if (tid < 384) \
    st_rlx_u64(ghb2 + (l) * 384 + tid, pk(pg[2 * tid] + pg[2 * tid + 1], (t))); \
  __syncthreads(); \
}

// peeled t=0 layer-0 gi in f32 (z ~1e7 overflows f16); one-time global reads.
#define F32DOT(UOFF, DST) { \
  const f16x2* wp_ = (const f16x2*)(wside + (size_t)(UOFF) * 64); \
  const float* xs_ = cur32 + (((UOFF) & 1) ? 64 : 0); \
  float a0_ = 0.f, a1_ = 0.f; \
  _Pragma("unroll") \
  for (int k_ = 0; k_ < 32; ++k_) { \
    f16x2 w_ = wp_[k_]; \
    a0_ += (float)w_[0] * xs_[2 * k_]; \
    a1_ += (float)w_[1] * xs_[2 * k_ + 1]; \
  } \
  DST = a0_ + a1_; }

__global__ __attribute__((amdgpu_flat_work_group_size(512, 512)))
__attribute__((amdgpu_waves_per_eu(2, 2))) void gru2_kernel(
    const f16* __restrict__ w16, const float* __restrict__ bih,
    const float* __restrict__ bhh, const float* __restrict__ zvec,
    float* __restrict__ enc, u64* __restrict__ hb2, u64* __restrict__ ghb2) {
  const int tid = threadIdx.x;

  __shared__ __align__(16) float4 wl[9216];   // 144 KB resident weights
  __shared__ __align__(16) float pg[768];     // 3 KB partials
  __shared__ __align__(16) f16 sxbuf[128];    // current phase src vector
  __shared__ float h32[4][128];               // gi: running h (f32)
  __shared__ float cur32[128];                // gi: z for peeled t=0

  const bool gi_role = (blockIdx.x == 0);
  const f16* wside = gi_role ? w16 : (w16 + 196608);

  // LDS-resident weights: units 480..767 of each layer, [layer][chunk][unit].
  for (int l = 0; l < 4; ++l)
    for (int i = tid; i < 2304; i += 512) {
      int c_ = i / 288, uu_ = (i % 288) + 480;
      wl[l * 2304 + i] =
          ((const float4*)(wside + (size_t)l * 49152 + (size_t)uu_ * 64))[c_];
    }

  if (gi_role) {
    float bs_r[4], bs_z[4], bi_n[4], bh_n[4];
    if (tid < 128) {
      #pragma unroll
      for (int l = 0; l < 4; ++l) {
        bs_r[l] = bih[l * 384 + tid] + bhh[l * 384 + tid];
        bs_z[l] = bih[l * 384 + 128 + tid] + bhh[l * 384 + 128 + tid];
        bi_n[l] = bih[l * 384 + 256 + tid];
        bh_n[l] = bhh[l * 384 + 256 + tid];
        h32[l][tid] = 0.f;
      }
      cur32[tid] = zvec[tid];
    }
    __syncthreads();

    // ---- peeled t = 0, phase 0: f32 path ----
    {
      GH_FETCH(0, 0)  // tags pre-init to 0, values 0
      float accA, accB = 0.f;
      F32DOT(tid, accA)
      if (tid >= 256) F32DOT(tid + 256, accB)
      pg[tid] = accA;
      if (tid >= 256) pg[tid + 256] = accB;
      __syncthreads();
      GI_GATE(0, 0)
      __syncthreads();
    }
    GI_PHASE(1, 0)
    GI_PHASE(2, 0)
    GI_PHASE(3, 0)

    #pragma unroll 1
    for (int t = 1; t < NEVT; ++t) {
      GI_PHASE(0, t)
      GI_PHASE(1, t)
      GI_PHASE(2, t)
      GI_PHASE(3, t)
    }
  } else {
    __syncthreads();
    #pragma unroll 1
    for (int t = 1; t < NEVT; ++t) {
      GH_PHASE(0, t)
      GH_PHASE(1, t)
      GH_PHASE(2, t)
      GH_PHASE(3, t)
    }
  }
}

// ---------------- Output heads ----------------
__global__ __launch_bounds__(128) void heads_kernel(
    const float* __restrict__ enc,
    const float* __restrict__ ah_w1, const float* __restrict__ ah_b1,
    const float* __restrict__ ah_w2, const float* __restrict__ ah_b2,
    const float* __restrict__ ah_w, const float* __restrict__ ah_b,
    const float* __restrict__ ph_w1, const float* __restrict__ ph_b1,
    const float* __restrict__ ph_w2, const float* __restrict__ ph_b2,
    const float* __restrict__ ph_w, const float* __restrict__ ph_b,
    const float* __restrict__ mh_w1, const float* __restrict__ mh_b1,
    const float* __restrict__ mh_w2, const float* __restrict__ mh_b2,
    const float* __restrict__ mh_w, const float* __restrict__ mh_b,
    float* __restrict__ oa, float* __restrict__ op, float* __restrict__ om) {
  const int u = threadIdx.x;
  const int r0 = blockIdx.x * 8;
  __shared__ float eb[8][128], xb[8][128], hb[8][128];
  #pragma unroll
  for (int r = 0; r < 8; ++r) eb[r][u] = enc[(size_t)(r0 + r) * 128 + u];
  // ---- atoms head ----
  #pragma unroll
  for (int r = 0; r < 8; ++r) xb[r][u] = eb[r][u];
  __syncthreads();
  for (int blk = 0; blk < 2; ++blk)
    res_block(xb, hb, ah_w1 + blk * 16384, ah_b1 + blk * 128,
              ah_w2 + blk * 16384, ah_b2 + blk * 128, u);
  {
    float acc[8];
    float bb = ah_b[u];
    #pragma unroll
    for (int r = 0; r < 8; ++r) acc[r] = bb;
    #pragma unroll 4
    for (int k = 0; k < 128; ++k) {
      float w = ah_w[u * 128 + k];
      #pragma unroll
      for (int r = 0; r < 8; ++r) acc[r] += w * xb[r][k];
    }
    #pragma unroll
    for (int r = 0; r < 8; ++r) oa[(size_t)(r0 + r) * 128 + u] = acc[r];
  }
  __syncthreads();
  // ---- pos head ----
  #pragma unroll
  for (int r = 0; r < 8; ++r) xb[r][u] = eb[r][u];
  __syncthreads();
  for (int blk = 0; blk < 2; ++blk)
    res_block(xb, hb, ph_w1 + blk * 16384, ph_b1 + blk * 128,
              ph_w2 + blk * 16384, ph_b2 + blk * 128, u);
  if (u < 8) {
    int r = u;
    float s = ph_b[0];
    for (int k = 0; k < 128; ++k) s += ph_w[k] * xb[r][k];
    s = s < 0.f ? 0.f : (s > 1.f ? 1.f : s);
    op[r0 + r] = s;
  }
  __syncthreads();
  // ---- mags head ----
  #pragma unroll
  for (int r = 0; r < 8; ++r) xb[r][u] = eb[r][u];
  __syncthreads();
  for (int blk = 0; blk < 2; ++blk)
    res_block(xb, hb, mh_w1 + blk * 16384, mh_b1 + blk * 128,
              mh_w2 + blk * 16384, mh_b2 + blk * 128, u);
  if (u < 8) {
    int r = u;
    float s = mh_b[0];
    for (int k = 0; k < 128; ++k) s += mh_w[k] * xb[r][k];
    om[r0 + r] = s;
  }
}

extern "C" void kernel_launch(void* const* d_in, const int* in_sizes, int n_in,
                              void* d_out, int out_size, void* d_ws, size_t ws_size,
                              hipStream_t stream) {
  const int* atom = (const int*)d_in[0];
  const float* tvec = (const float*)d_in[1];
  const float* mvec = (const float*)d_in[2];
  const float* atom_emb = (const float*)d_in[3];
  const float* mag_w = (const float*)d_in[4];
  const float* mag_b = (const float*)d_in[5];
  const float* pos_w = (const float*)d_in[6];
  const float* pos_b = (const float*)d_in[7];
  const float* reduce_w = (const float*)d_in[8];
  const float* reduce_b = (const float*)d_in[9];
  const float* net_w1 = (const float*)d_in[10];
  const float* net_b1 = (const float*)d_in[11];
  const float* net_w2 = (const float*)d_in[12];
  const float* net_b2 = (const float*)d_in[13];
  const float* final_w = (const float*)d_in[14];
  const float* final_b = (const float*)d_in[15];
  const float* redg_w = (const float*)d_in[16];
  const float* redg_b = (const float*)d_in[17];
  const float* wg_w1 = (const float*)d_in[18];
  const float* wg_b1 = (const float*)d_in[19];
  const float* wg_w2 = (const float*)d_in[20];
  const float* wg_b2 = (const float*)d_in[21];
  const float* gfinal_w = (const float*)d_in[22];
  const float* gfinal_b = (const float*)d_in[23];
  const float* gru_wih = (const float*)d_in[24];
  const float* gru_whh = (const float*)d_in[25];
  const float* gru_bih = (const float*)d_in[26];
  const float* gru_bhh = (const float*)d_in[27];
  const float* ah_w1 = (const float*)d_in[28];
  const float* ah_b1 = (const float*)d_in[29];
  const float* ah_w2 = (const float*)d_in[30];
  const float* ah_b2 = (const float*)d_in[31];
  const float* ah_w = (const float*)d_in[32];
  const float* ah_b = (const float*)d_in[33];
  const float* ph_w1 = (const float*)d_in[34];
  const float* ph_b1 = (const float*)d_in[35];
  const float* ph_w2 = (const float*)d_in[36];
  const float* ph_b2 = (const float*)d_in[37];
  const float* ph_w = (const float*)d_in[38];
  const float* ph_b = (const float*)d_in[39];
  const float* mh_w1 = (const float*)d_in[40];
  const float* mh_b1 = (const float*)d_in[41];
  const float* mh_w2 = (const float*)d_in[42];
  const float* mh_b2 = (const float*)d_in[43];
  const float* mh_w = (const float*)d_in[44];
  const float* mh_b = (const float*)d_in[45];

  float* out = (float*)d_out;
  float* oa = out;                        // atoms [N,128]
  float* op = out + (size_t)NEVT * 128;   // pos [N]
  float* om = op + NEVT;                  // mags [N]
  float* oz = om + NEVT;                  // z [128]

  float* enc = (float*)d_ws;              // encodings [N,128] : 16 MB
  float* pg = enc + (size_t)NEVT * 128;   // stage-1 partials: 2 MB (reused for w16)
  float* pz = pg + (size_t)NBLK * 128;    // stage-2 partials: 2 MB
  float* gv = pz + (size_t)NBLK * 128;    // g [128]
  float* xf = oa;  // stage-1 output staged in atoms region; heads overwrite later

  // f16 weight copies overlay the pg region once pg has been reduced into gv.
  f16* w16i = (f16*)pg;                   // 384 KB
  f16* w16h = w16i + 196608;              // 384 KB (contiguous with w16i)

  // cross-CU comm: tagged 8-byte words, after gv.
  u64* hb2 = (u64*)(gv + 128);            // [4][128] h values
  u64* ghb2 = hb2 + 512;                  // [4][384] gh row sums

  enc1_kernel<<<NBLK, 128, 0, stream>>>(atom, tvec, mvec, atom_emb, mag_w, mag_b,
      pos_w, pos_b, reduce_w, reduce_b, net_w1, net_b1, net_w2, net_b2,
      final_w, final_b, xf, pg);
  reduce_kernel<<<1, 1024, 0, stream>>>(pg, NBLK, gv);
  wprep_kernel<<<768, 256, 0, stream>>>(gru_wih, gru_whh, w16i, w16h, hb2, ghb2);
  enc2_kernel<<<NBLK, 128, 0, stream>>>(xf, gv, redg_w, redg_b, wg_w1, wg_b1,
      wg_w2, wg_b2, gfinal_w, gfinal_b, pz);
  reduce_kernel<<<1, 1024, 0, stream>>>(pz, NBLK, oz);
  gru2_kernel<<<2, 512, 0, stream>>>(w16i, gru_bih, gru_bhh, oz, enc, hb2, ghb2);
  heads_kernel<<<NBLK, 128, 0, stream>>>(enc, ah_w1, ah_b1, ah_w2, ah_b2, ah_w, ah_b,
      ph_w1, ph_b1, ph_w2, ph_b2, ph_w, ph_b, mh_w1, mh_b1, mh_w2, mh_b2, mh_w, mh_b,
      oa, op, om);
}

// Round 7
// 132020.044 us; speedup vs baseline: 3.2148x; 2.4247x over previous
//
#include <hip/hip_runtime.h>
#include <hip/hip_bf16.h>

#define NEVT 32768
#define NBLK (NEVT / 8)

typedef _Float16 f16;
typedef _Float16 f16x2 __attribute__((ext_vector_type(2)));
typedef float f32x16 __attribute__((ext_vector_type(16)));
typedef float Row128[128];

#ifndef __has_builtin
#define __has_builtin(x) 0
#endif

__device__ __forceinline__ float dot2f(f16x2 a, f16x2 b, float c) {
#if __has_builtin(__builtin_amdgcn_fdot2)
  return __builtin_amdgcn_fdot2(a, b, c, false);
#else
  return c + (float)a[0] * (float)b[0] + (float)a[1] * (float)b[1];
#endif
}

__device__ __forceinline__ float lrelu(float v) { return v >= 0.f ? v : 0.2f * v; }

__device__ __forceinline__ float sigmoidf(float x) {
  return 1.f / (1.f + __expf(-x));
}

__device__ __forceinline__ float tanh_f(float x) {
  float ax = fabsf(x);
  float e = __expf(-2.f * ax);
  float t = (1.f - e) / (1.f + e);
  return x >= 0.f ? t : -t;
}

// One residual block on an 8-row tile held in LDS. 128 threads, thread u owns
// output unit u. Two internal barriers.
__device__ __forceinline__ void res_block(Row128* xb, Row128* hb,
    const float* __restrict__ w1, const float* __restrict__ b1,
    const float* __restrict__ w2, const float* __restrict__ b2, int u) {
  float acc[8];
  float bb = b1[u];
  #pragma unroll
  for (int r = 0; r < 8; ++r) acc[r] = bb;
  #pragma unroll 4
  for (int k = 0; k < 128; ++k) {
    float w = w1[u * 128 + k];
    #pragma unroll
    for (int r = 0; r < 8; ++r) acc[r] += w * xb[r][k];
  }
  #pragma unroll
  for (int r = 0; r < 8; ++r) hb[r][u] = lrelu(acc[r]);
  __syncthreads();
  bb = b2[u];
  #pragma unroll
  for (int r = 0; r < 8; ++r) acc[r] = bb;
  #pragma unroll 4
  for (int k = 0; k < 128; ++k) {
    float w = w2[u * 128 + k];
    #pragma unroll
    for (int r = 0; r < 8; ++r) acc[r] += w * hb[r][k];
  }
  #pragma unroll
  for (int r = 0; r < 8; ++r) xb[r][u] = lrelu(xb[r][u] + acc[r]);
  __syncthreads();
}

// ---------------- Encoder stage 1 ----------------
__global__ __launch_bounds__(128) void enc1_kernel(
    const int* __restrict__ atom, const float* __restrict__ tvec,
    const float* __restrict__ mvec, const float* __restrict__ atom_emb,
    const float* __restrict__ mag_w, const float* __restrict__ mag_b,
    const float* __restrict__ pos_w, const float* __restrict__ pos_b,
    const float* __restrict__ reduce_w, const float* __restrict__ reduce_b,
    const float* __restrict__ net_w1, const float* __restrict__ net_b1,
    const float* __restrict__ net_w2, const float* __restrict__ net_b2,
    const float* __restrict__ final_w, const float* __restrict__ final_b,
    float* __restrict__ xf, float* __restrict__ pg) {
  const int u = threadIdx.x;
  const int r0 = blockIdx.x * 8;
  __shared__ float xin[8][384];
  __shared__ float xb[8][128];
  __shared__ float hb[8][128];
  #pragma unroll
  for (int r = 0; r < 8; ++r) {
    int row = r0 + r;
    xin[r][u] = atom_emb[atom[row] * 128 + u];
    xin[r][128 + u] = tvec[row] * pos_w[u] + pos_b[u];
    xin[r][256 + u] = mvec[row] * mag_w[u] + mag_b[u];
  }
  __syncthreads();
  float acc[8];
  float bb = reduce_b[u];
  #pragma unroll
  for (int r = 0; r < 8; ++r) acc[r] = bb;
  #pragma unroll 4
  for (int k = 0; k < 384; ++k) {
    float w = reduce_w[u * 384 + k];
    #pragma unroll
    for (int r = 0; r < 8; ++r) acc[r] += w * xin[r][k];
  }
  #pragma unroll
  for (int r = 0; r < 8; ++r) xb[r][u] = acc[r];
  __syncthreads();
  for (int blk = 0; blk < 4; ++blk)
    res_block(xb, hb, net_w1 + blk * 16384, net_b1 + blk * 128,
              net_w2 + blk * 16384, net_b2 + blk * 128, u);
  bb = final_b[u];
  #pragma unroll
  for (int r = 0; r < 8; ++r) acc[r] = bb;
  #pragma unroll 4
  for (int k = 0; k < 128; ++k) {
    float w = final_w[u * 128 + k];
    #pragma unroll
    for (int r = 0; r < 8; ++r) acc[r] += w * xb[r][k];
  }
  float s = 0.f;
  #pragma unroll
  for (int r = 0; r < 8; ++r) {
    xf[(r0 + r) * 128 + u] = acc[r];
    s += acc[r];
  }
  pg[blockIdx.x * 128 + u] = s;
}

// ---------------- Deterministic column reduction: sum m rows of [128] -------
__global__ __launch_bounds__(1024) void reduce_kernel(
    const float* __restrict__ src, int m, float* __restrict__ dst) {
  int u = threadIdx.x & 127, c = threadIdx.x >> 7;
  float s = 0.f;
  for (int i = c; i < m; i += 8) s += src[i * 128 + u];
  __shared__ float tmp[8][128];
  tmp[c][u] = s;
  __syncthreads();
  if (c == 0) {
    float t = 0.f;
    #pragma unroll
    for (int j = 0; j < 8; ++j) t += tmp[j][u];
    dst[u] = t;
  }
}

// ---------------- Encoder stage 2 ----------------
__global__ __launch_bounds__(128) void enc2_kernel(
    const float* __restrict__ xf, const float* __restrict__ g,
    const float* __restrict__ redg_w, const float* __restrict__ redg_b,
    const float* __restrict__ wg_w1, const float* __restrict__ wg_b1,
    const float* __restrict__ wg_w2, const float* __restrict__ wg_b2,
    const float* __restrict__ gfinal_w, const float* __restrict__ gfinal_b,
    float* __restrict__ pz) {
  const int u = threadIdx.x;
  const int r0 = blockIdx.x * 8;
  __shared__ float xin[8][256];
  __shared__ float xb[8][128];
  __shared__ float hb[8][128];
  #pragma unroll
  for (int r = 0; r < 8; ++r) {
    xin[r][u] = xf[(r0 + r) * 128 + u];
    xin[r][128 + u] = g[u];
  }
  __syncthreads();
  float acc[8];
  float bb = redg_b[u];
  #pragma unroll
  for (int r = 0; r < 8; ++r) acc[r] = bb;
  #pragma unroll 4
  for (int k = 0; k < 256; ++k) {
    float w = redg_w[u * 256 + k];
    #pragma unroll
    for (int r = 0; r < 8; ++r) acc[r] += w * xin[r][k];
  }
  #pragma unroll
  for (int r = 0; r < 8; ++r) xb[r][u] = acc[r];
  __syncthreads();
  for (int blk = 0; blk < 4; ++blk)
    res_block(xb, hb, wg_w1 + blk * 16384, wg_b1 + blk * 128,
              wg_w2 + blk * 16384, wg_b2 + blk * 128, u);
  bb = gfinal_b[u];
  #pragma unroll
  for (int r = 0; r < 8; ++r) acc[r] = bb;
  #pragma unroll 4
  for (int k = 0; k < 128; ++k) {
    float w = gfinal_w[u * 128 + k];
    #pragma unroll
    for (int r = 0; r < 8; ++r) acc[r] += w * xb[r][k];
  }
  float s = 0.f;
  #pragma unroll
  for (int r = 0; r < 8; ++r) s += acc[r];
  pz[blockIdx.x * 128 + u] = s;
}

// ---------------- Weight pre-conversion f32 -> f16 ----------------
__global__ __launch_bounds__(256) void wprep_kernel(
    const float* __restrict__ wih, const float* __restrict__ whh,
    f16* __restrict__ w16i, f16* __restrict__ w16h) {
  int idx = blockIdx.x * 256 + threadIdx.x;
  if (idx < 196608) {
    w16i[idx] = (f16)wih[idx];
    w16h[idx] = (f16)whh[idx];
  }
}

// ---------------- Sequential GRU decoder (single workgroup, 512 threads) ----
// R10: COMPILER-MANAGED AGPR residency. Ledger: R4-R6 showed the allocator
// caps ARCH VGPRs at 128/lane (512 thr, waves_per_eu(2,2)) and spills any
// anchored demand beyond it; R7 showed hard-coded physical AGPRs collide
// with the compiler's own AGPR spill slots (NaN); R8 (fp8 decode) and R9
// (cross-CU handshake) attacked the wrong resource. The unified file gives
// 256 regs/lane at this occupancy; the AGPR half (128/lane) is idle in a
// no-MFMA kernel. The sound mechanism is the "a" register-CLASS constraint:
// the allocator itself assigns virtual AGPR tuples (no collision), VALU
// access is compiled as v_accvgpr_read (or direct AGPR src), and spilling
// them would be strictly worse than keeping them (their slots ARE the spill
// space).
// Placement per thread (12 row-units x 32 dw):
//   AGPR (128 dw, "+a" anchors): A-rows, layers 0..3  (256 KB chip-wide)
//   LDS  (128 KB)              : B-rows, layers 2,3   (R6's layout)
//   L2 stream (384 KB/step)    : B-rows layers 0,1 + C-rows layers 0..3
// Stream arithmetic: 384 KB @ ~100 B/cyc ~= 3900 cyc/step (vs 7700 at R0's
// 786 KB), VALU ~2300 cyc hidden beneath it, gates ~600.

#define PW(WV, K) __builtin_bit_cast(f16x2, (WV)[(K)])

#define D4(WV, B, Q, A) \
  A = dot2f(PW(WV,(B)+0), __builtin_bit_cast(f16x2,(Q).x), A); \
  A = dot2f(PW(WV,(B)+1), __builtin_bit_cast(f16x2,(Q).y), A); \
  A = dot2f(PW(WV,(B)+2), __builtin_bit_cast(f16x2,(Q).z), A); \
  A = dot2f(PW(WV,(B)+3), __builtin_bit_cast(f16x2,(Q).w), A);

#define D4Q(WQ, Q, A) \
  A = dot2f(__builtin_bit_cast(f16x2,(WQ).x), __builtin_bit_cast(f16x2,(Q).x), A); \
  A = dot2f(__builtin_bit_cast(f16x2,(WQ).y), __builtin_bit_cast(f16x2,(Q).y), A); \
  A = dot2f(__builtin_bit_cast(f16x2,(WQ).z), __builtin_bit_cast(f16x2,(Q).z), A); \
  A = dot2f(__builtin_bit_cast(f16x2,(WQ).w), __builtin_bit_cast(f16x2,(Q).w), A);

#define F32T(WV, K, XS, OFF) { f16x2 p_ = PW(WV, (K)); \
  a0_ += (float)p_[0] * (XS)[(OFF) + 2*(K)]; \
  a1_ += (float)p_[1] * (XS)[(OFF) + 2*(K) + 1]; }

#define F32T16(WV, XS, OFF) \
  F32T(WV,0,XS,OFF) F32T(WV,1,XS,OFF) F32T(WV,2,XS,OFF) F32T(WV,3,XS,OFF) \
  F32T(WV,4,XS,OFF) F32T(WV,5,XS,OFF) F32T(WV,6,XS,OFF) F32T(WV,7,XS,OFF) \
  F32T(WV,8,XS,OFF) F32T(WV,9,XS,OFF) F32T(WV,10,XS,OFF) F32T(WV,11,XS,OFF) \
  F32T(WV,12,XS,OFF) F32T(WV,13,XS,OFF) F32T(WV,14,XS,OFF) F32T(WV,15,XS,OFF)

#define L4(WV, I, Q) \
  (WV)[4*(I)+0] = (Q).x; (WV)[4*(I)+1] = (Q).y; \
  (WV)[4*(I)+2] = (Q).z; (WV)[4*(I)+3] = (Q).w;

#define LOAD_W16(WA, WB, BASE) do { \
  const float4* p_ = (const float4*)(BASE); \
  float4 q0_ = p_[0], q1_ = p_[1], q2_ = p_[2], q3_ = p_[3]; \
  float4 q4_ = p_[4], q5_ = p_[5], q6_ = p_[6], q7_ = p_[7]; \
  L4(WA, 0, q0_) L4(WA, 1, q1_) L4(WA, 2, q2_) L4(WA, 3, q3_) \
  L4(WB, 0, q4_) L4(WB, 1, q5_) L4(WB, 2, q6_) L4(WB, 3, q7_) \
} while (0)

// Phase header/tail. srcbuf (f16): [0,128)=cur, [128+l*128,...)=h16[l].
// pg (float): [0,768)=gi partials (row*2+half), [768,1536)=gh.
#define PH_HEAD(L) \
  const float4* s4_ = (const float4*)(srcf + soff_base + (L) * sideOff); \
  float aA0_=0.f,aA1_=0.f,aB0_=0.f,aB1_=0.f,aC0_=0.f,aC1_=0.f; \
  float4 q0_, q1_, wq0_, wq1_, wr0_, wr1_;

#define PH_TAIL() \
  pgf[d0] = aA0_ + aA1_; pgf[d0+2] = aB0_ + aB1_; pgf[d0+4] = aC0_ + aC1_;

// Layers 0,1: A from AGPR; B and C streamed from L2. Processed in 4 groups
// of (2 src-quads, 2 B-quads, 2 C-quads) to cap live stream registers.
#define PH_ST(L, Aa, Ab) do { PH_HEAD(L) \
  const float4* wb4_ = (const float4*)(w16 + wAb_ + (L)*49152 + 128); \
  const float4* wc4_ = (const float4*)(w16 + wAb_ + (L)*49152 + 256); \
  q0_=s4_[0]; q1_=s4_[1]; wq0_=wb4_[0]; wq1_=wb4_[1]; wr0_=wc4_[0]; wr1_=wc4_[1]; \
  D4(Aa,0,q0_,aA0_) D4(Aa,4,q1_,aA1_) D4Q(wq0_,q0_,aB0_) D4Q(wq1_,q1_,aB1_) \
  D4Q(wr0_,q0_,aC0_) D4Q(wr1_,q1_,aC1_) \
  q0_=s4_[2]; q1_=s4_[3]; wq0_=wb4_[2]; wq1_=wb4_[3]; wr0_=wc4_[2]; wr1_=wc4_[3]; \
  D4(Aa,8,q0_,aA0_) D4(Aa,12,q1_,aA1_) D4Q(wq0_,q0_,aB0_) D4Q(wq1_,q1_,aB1_) \
  D4Q(wr0_,q0_,aC0_) D4Q(wr1_,q1_,aC1_) \
  q0_=s4_[4]; q1_=s4_[5]; wq0_=wb4_[4]; wq1_=wb4_[5]; wr0_=wc4_[4]; wr1_=wc4_[5]; \
  D4(Ab,0,q0_,aA0_) D4(Ab,4,q1_,aA1_) D4Q(wq0_,q0_,aB0_) D4Q(wq1_,q1_,aB1_) \
  D4Q(wr0_,q0_,aC0_) D4Q(wr1_,q1_,aC1_) \
  q0_=s4_[6]; q1_=s4_[7]; wq0_=wb4_[6]; wq1_=wb4_[7]; wr0_=wc4_[6]; wr1_=wc4_[7]; \
  D4(Ab,8,q0_,aA0_) D4(Ab,12,q1_,aA1_) D4Q(wq0_,q0_,aB0_) D4Q(wq1_,q1_,aB1_) \
  D4Q(wr0_,q0_,aC0_) D4Q(wr1_,q1_,aC1_) \
  PH_TAIL() } while (0)

// Layers 2,3: A from AGPR, B from LDS, C streamed.
#define PH_L(L, Aa, Ab, WL) do { PH_HEAD(L) \
  const float4* wc4_ = (const float4*)(w16 + wAb_ + (L)*49152 + 256); \
  float4 bw0_, bw1_; \
  q0_=s4_[0]; q1_=s4_[1]; wr0_=wc4_[0]; wr1_=wc4_[1]; \
  bw0_=(WL)[0*512+tid]; bw1_=(WL)[1*512+tid]; \
  D4(Aa,0,q0_,aA0_) D4(Aa,4,q1_,aA1_) D4Q(bw0_,q0_,aB0_) D4Q(bw1_,q1_,aB1_) \
  D4Q(wr0_,q0_,aC0_) D4Q(wr1_,q1_,aC1_) \
  q0_=s4_[2]; q1_=s4_[3]; wr0_=wc4_[2]; wr1_=wc4_[3]; \
  bw0_=(WL)[2*512+tid]; bw1_=(WL)[3*512+tid]; \
  D4(Aa,8,q0_,aA0_) D4(Aa,12,q1_,aA1_) D4Q(bw0_,q0_,aB0_) D4Q(bw1_,q1_,aB1_) \
  D4Q(wr0_,q0_,aC0_) D4Q(wr1_,q1_,aC1_) \
  q0_=s4_[4]; q1_=s4_[5]; wr0_=wc4_[4]; wr1_=wc4_[5]; \
  bw0_=(WL)[4*512+tid]; bw1_=(WL)[5*512+tid]; \
  D4(Ab,0,q0_,aA0_) D4(Ab,4,q1_,aA1_) D4Q(bw0_,q0_,aB0_) D4Q(bw1_,q1_,aB1_) \
  D4Q(wr0_,q0_,aC0_) D4Q(wr1_,q1_,aC1_) \
  q0_=s4_[6]; q1_=s4_[7]; wr0_=wc4_[6]; wr1_=wc4_[7]; \
  bw0_=(WL)[6*512+tid]; bw1_=(WL)[7*512+tid]; \
  D4(Ab,8,q0_,aA0_) D4(Ab,12,q1_,aA1_) D4Q(bw0_,q0_,aB0_) D4Q(bw1_,q1_,aB1_) \
  D4Q(wr0_,q0_,aC0_) D4Q(wr1_,q1_,aC1_) \
  PH_TAIL() } while (0)

#define GATE(L, T) \
  if (tid < 128) { \
    const float2* gi2_ = (const float2*)pgf; \
    const float2* gh2_ = (const float2*)(pgf + 768); \
    float2 ar_ = gi2_[tid],      br_ = gh2_[tid]; \
    float2 az_ = gi2_[128+tid],  bz_ = gh2_[128+tid]; \
    float2 an_ = gi2_[256+tid],  bn_ = gh2_[256+tid]; \
    float r_ = sigmoidf((ar_.x + ar_.y) + (br_.x + br_.y) + bsum_r[L][tid]); \
    float z_ = sigmoidf((az_.x + az_.y) + (bz_.x + bz_.y) + bsum_z[L][tid]); \
    float n_ = tanh_f((an_.x + an_.y) + b_in[L][tid] + \
                      r_ * ((bn_.x + bn_.y) + b_hn[L][tid])); \
    float h_ = (1.f - z_) * n_ + z_ * h32[L][tid]; \
    h32[L][tid] = h_; f16 hh_ = (f16)h_; \
    srcbuf[(1 + (L)) * 128 + tid] = hh_; srcbuf[tid] = hh_; \
    if ((L) == 3) enc[(size_t)(T) * 128 + tid] = h_; \
  }

__global__ __attribute__((amdgpu_flat_work_group_size(512, 512)))
__attribute__((amdgpu_waves_per_eu(2, 2))) void gru_kernel(
    const f16* __restrict__ w16, const float* __restrict__ bih,
    const float* __restrict__ bhh, const float* __restrict__ zvec,
    float* __restrict__ enc) {
  const int tid = threadIdx.x;

  __shared__ __align__(16) float4 wldsB2[4096];       // 64 KB: B-rows layer 2
  __shared__ __align__(16) float4 wldsB3[4096];       // 64 KB: B-rows layer 3
  __shared__ __align__(16) float pgbuf[1536];         // 6 KB
  __shared__ __align__(16) f16 srcbuf[640];           // 1.25 KB
  __shared__ __align__(16) float h32[4][128];         // 2 KB
  __shared__ __align__(16) float cur32[128];          // 0.5 KB
  __shared__ float bsum_r[4][128], bsum_z[4][128];    // 4 KB
  __shared__ float b_in[4][128], b_hn[4][128];        // 4 KB

  float* const pgf = pgbuf;
  const f16* const srcf = srcbuf;

  // Row-grouped unit mapping (validated in R6).
  const int side = tid >> 8;           // 0 = gi (W_ih), 1 = gh (W_hh)
  const int ti = tid & 255;
  const int half = ti & 1;
  const int hs = half * 64;
  const int rb = 3 * (ti >> 1);        // rows rb, rb+1, rb+2 of [0,384)
  const int d0 = side * 768 + rb * 2 + half;
  const int soff_base = side ? (128 + hs) : hs;
  const int sideOff = side * 128;
  const int wAb_ = side * 196608 + rb * 128 + hs;  // A-row elem base, layer 0

  // AGPR-resident weights: A-rows of layers 0..3 (8 x f32x16 = 128 regs).
  // "+a" = AGPR register CLASS; the allocator assigns virtual tuples, so no
  // collision with its own spill machinery (the R7 failure mode).
  f32x16 rA0a, rA0b, rA1a, rA1b, rA2a, rA2b, rA3a, rA3b;
  LOAD_W16(rA0a, rA0b, w16 + wAb_);
  LOAD_W16(rA1a, rA1b, w16 + wAb_ + 49152);
  LOAD_W16(rA2a, rA2b, w16 + wAb_ + 2 * 49152);
  LOAD_W16(rA3a, rA3b, w16 + wAb_ + 3 * 49152);
  asm volatile("" : "+a"(rA0a), "+a"(rA0b), "+a"(rA1a), "+a"(rA1b));
  asm volatile("" : "+a"(rA2a), "+a"(rA2b), "+a"(rA3a), "+a"(rA3b));

  // LDS-resident weights: B-rows layers 2,3. [chunk][tid] so a wave's
  // ds_read_b128 is lane-contiguous (conflict-free).
  {
    const float4* p2 = (const float4*)(w16 + wAb_ + 2 * 49152 + 128);
    const float4* p3 = (const float4*)(w16 + wAb_ + 3 * 49152 + 128);
    #pragma unroll
    for (int c = 0; c < 8; ++c) {
      wldsB2[c * 512 + tid] = p2[c];
      wldsB3[c * 512 + tid] = p3[c];
    }
  }

  if (tid < 128) {
    cur32[tid] = zvec[tid];
    srcbuf[tid] = (f16)0.f;
    #pragma unroll
    for (int l = 0; l < 4; ++l) {
      h32[l][tid] = 0.f;
      srcbuf[(1 + l) * 128 + tid] = (f16)0.f;
    }
  }
  {
    int l_ = tid >> 7, row_ = tid & 127;
    bsum_r[l_][row_] = bih[l_*384 + row_]       + bhh[l_*384 + row_];
    bsum_z[l_][row_] = bih[l_*384 + 128 + row_] + bhh[l_*384 + 128 + row_];
    b_in[l_][row_]   = bih[l_*384 + 256 + row_];
    b_hn[l_][row_]   = bhh[l_*384 + 256 + row_];
  }
  __syncthreads();

  // ---- peeled step t = 0: layer-0 gi in f32 (z ~1e7 overflows f16) ----
  {
    if (tid < 256) {  // side == 0: f32 path; A from AGPR, B/C one-time global
      const float* xs_ = cur32 + hs;
      { float a0_ = 0.f, a1_ = 0.f;
        F32T16(rA0a, xs_, 0) F32T16(rA0b, xs_, 32)
        pgf[d0] = a0_ + a1_; }
      { float a0_ = 0.f, a1_ = 0.f;
        const f16x2* wp_ = (const f16x2*)(w16 + wAb_ + 128);
        #pragma unroll
        for (int k = 0; k < 32; ++k) { f16x2 w_ = wp_[k];
          a0_ += (float)w_[0] * xs_[2*k]; a1_ += (float)w_[1] * xs_[2*k+1]; }
        pgf[d0 + 2] = a0_ + a1_; }
      { float a0_ = 0.f, a1_ = 0.f;
        const f16x2* wp_ = (const f16x2*)(w16 + wAb_ + 256);
        #pragma unroll
        for (int k = 0; k < 32; ++k) { f16x2 w_ = wp_[k];
          a0_ += (float)w_[0] * xs_[2*k]; a1_ += (float)w_[1] * xs_[2*k+1]; }
        pgf[d0 + 4] = a0_ + a1_; }
    } else {          // side == 1: h16 == 0 -> normal path yields zeros
      PH_ST(0, rA0a, rA0b);
    }
    __syncthreads();
    GATE(0, 0)
    __syncthreads();
    PH_ST(1, rA1a, rA1b);
    __syncthreads();
    GATE(1, 0)
    __syncthreads();
    PH_L(2, rA2a, rA2b, wldsB2);
    __syncthreads();
    GATE(2, 0)
    __syncthreads();
    PH_L(3, rA3a, rA3b, wldsB3);
    __syncthreads();
    GATE(3, 0)
    __syncthreads();
  }

  #pragma unroll 1
  for (int t = 1; t < NEVT; ++t) {
    PH_ST(0, rA0a, rA0b);
    __syncthreads();
    GATE(0, t)
    __syncthreads();
    PH_ST(1, rA1a, rA1b);
    __syncthreads();
    GATE(1, t)
    __syncthreads();
    PH_L(2, rA2a, rA2b, wldsB2);
    __syncthreads();
    GATE(2, t)
    __syncthreads();
    PH_L(3, rA3a, rA3b, wldsB3);
    __syncthreads();
    GATE(3, t)
    __syncthreads();
  }

  // Keep the AGPR live range spanning the whole loop.
  asm volatile("" :: "a"(rA0a), "a"(rA0b), "a"(rA1a), "a"(rA1b),
                     "a"(rA2a), "a"(rA2b), "a"(rA3a), "a"(rA3b));
}

// ---------------- Output heads ----------------
__global__ __launch_bounds__(128) void heads_kernel(
    const float* __restrict__ enc,
    const float* __restrict__ ah_w1, const float* __restrict__ ah_b1,
    const float* __restrict__ ah_w2, const float* __restrict__ ah_b2,
    const float* __restrict__ ah_w, const float* __restrict__ ah_b,
    const float* __restrict__ ph_w1, const float* __restrict__ ph_b1,
    const float* __restrict__ ph_w2, const float* __restrict__ ph_b2,
    const float* __restrict__ ph_w, const float* __restrict__ ph_b,
    const float* __restrict__ mh_w1, const float* __restrict__ mh_b1,
    const float* __restrict__ mh_w2, const float* __restrict__ mh_b2,
    const float* __restrict__ mh_w, const float* __restrict__ mh_b,
    float* __restrict__ oa, float* __restrict__ op, float* __restrict__ om) {
  const int u = threadIdx.x;
  const int r0 = blockIdx.x * 8;
  __shared__ float eb[8][128], xb[8][128], hb[8][128];
  #pragma unroll
  for (int r = 0; r < 8; ++r) eb[r][u] = enc[(size_t)(r0 + r) * 128 + u];
  // ---- atoms head ----
  #pragma unroll
  for (int r = 0; r < 8; ++r) xb[r][u] = eb[r][u];
  __syncthreads();
  for (int blk = 0; blk < 2; ++blk)
    res_block(xb, hb, ah_w1 + blk * 16384, ah_b1 + blk * 128,
              ah_w2 + blk * 16384, ah_b2 + blk * 128, u);
  {
    float acc[8];
    float bb = ah_b[u];
    #pragma unroll
    for (int r = 0; r < 8; ++r) acc[r] = bb;
    #pragma unroll 4
    for (int k = 0; k < 128; ++k) {
      float w = ah_w[u * 128 + k];
      #pragma unroll
      for (int r = 0; r < 8; ++r) acc[r] += w * xb[r][k];
    }
    #pragma unroll
    for (int r = 0; r < 8; ++r) oa[(size_t)(r0 + r) * 128 + u] = acc[r];
  }
  __syncthreads();
  // ---- pos head ----
  #pragma unroll
  for (int r = 0; r < 8; ++r) xb[r][u] = eb[r][u];
  __syncthreads();
  for (int blk = 0; blk < 2; ++blk)
    res_block(xb, hb, ph_w1 + blk * 16384, ph_b1 + blk * 128,
              ph_w2 + blk * 16384, ph_b2 + blk * 128, u);
  if (u < 8) {
    int r = u;
    float s = ph_b[0];
    for (int k = 0; k < 128; ++k) s += ph_w[k] * xb[r][k];
    s = s < 0.f ? 0.f : (s > 1.f ? 1.f : s);
    op[r0 + r] = s;
  }
  __syncthreads();
  // ---- mags head ----
  #pragma unroll
  for (int r = 0; r < 8; ++r) xb[r][u] = eb[r][u];
  __syncthreads();
  for (int blk = 0; blk < 2; ++blk)
    res_block(xb, hb, mh_w1 + blk * 16384, mh_b1 + blk * 128,
              mh_w2 + blk * 16384, mh_b2 + blk * 128, u);
  if (u < 8) {
    int r = u;
    float s = mh_b[0];
    for (int k = 0; k < 128; ++k) s += mh_w[k] * xb[r][k];
    om[r0 + r] = s;
  }
}

extern "C" void kernel_launch(void* const* d_in, const int* in_sizes, int n_in,
                              void* d_out, int out_size, void* d_ws, size_t ws_size,
                              hipStream_t stream) {
  const int* atom = (const int*)d_in[0];
  const float* tvec = (const float*)d_in[1];
  const float* mvec = (const float*)d_in[2];
  const float* atom_emb = (const float*)d_in[3];
  const float* mag_w = (const float*)d_in[4];
  const float* mag_b = (const float*)d_in[5];
  const float* pos_w = (const float*)d_in[6];
  const float* pos_b = (const float*)d_in[7];
  const float* reduce_w = (const float*)d_in[8];
  const float* reduce_b = (const float*)d_in[9];
  const float* net_w1 = (const float*)d_in[10];
  const float* net_b1 = (const float*)d_in[11];
  const float* net_w2 = (const float*)d_in[12];
  const float* net_b2 = (const float*)d_in[13];
  const float* final_w = (const float*)d_in[14];
  const float* final_b = (const float*)d_in[15];
  const float* redg_w = (const float*)d_in[16];
  const float* redg_b = (const float*)d_in[17];
  const float* wg_w1 = (const float*)d_in[18];
  const float* wg_b1 = (const float*)d_in[19];
  const float* wg_w2 = (const float*)d_in[20];
  const float* wg_b2 = (const float*)d_in[21];
  const float* gfinal_w = (const float*)d_in[22];
  const float* gfinal_b = (const float*)d_in[23];
  const float* gru_wih = (const float*)d_in[24];
  const float* gru_whh = (const float*)d_in[25];
  const float* gru_bih = (const float*)d_in[26];
  const float* gru_bhh = (const float*)d_in[27];
  const float* ah_w1 = (const float*)d_in[28];
  const float* ah_b1 = (const float*)d_in[29];
  const float* ah_w2 = (const float*)d_in[30];
  const float* ah_b2 = (const float*)d_in[31];
  const float* ah_w = (const float*)d_in[32];
  const float* ah_b = (const float*)d_in[33];
  const float* ph_w1 = (const float*)d_in[34];
  const float* ph_b1 = (const float*)d_in[35];
  const float* ph_w2 = (const float*)d_in[36];
  const float* ph_b2 = (const float*)d_in[37];
  const float* ph_w = (const float*)d_in[38];
  const float* ph_b = (const float*)d_in[39];
  const float* mh_w1 = (const float*)d_in[40];
  const float* mh_b1 = (const float*)d_in[41];
  const float* mh_w2 = (const float*)d_in[42];
  const float* mh_b2 = (const float*)d_in[43];
  const float* mh_w = (const float*)d_in[44];
  const float* mh_b = (const float*)d_in[45];

  float* out = (float*)d_out;
  float* oa = out;                        // atoms [N,128]
  float* op = out + (size_t)NEVT * 128;   // pos [N]
  float* om = op + NEVT;                  // mags [N]
  float* oz = om + NEVT;                  // z [128]

  float* enc = (float*)d_ws;              // encodings [N,128] : 16 MB
  float* pg = enc + (size_t)NEVT * 128;   // stage-1 partials: 2 MB (reused for w16)
  float* pz = pg + (size_t)NBLK * 128;    // stage-2 partials: 2 MB
  float* gv = pz + (size_t)NBLK * 128;    // g [128]
  float* xf = oa;  // stage-1 output staged in atoms region; heads overwrite later

  // f16 weight copies overlay the pg region once pg has been reduced into gv.
  f16* w16i = (f16*)pg;                   // 384 KB
  f16* w16h = w16i + 196608;              // 384 KB (contiguous with w16i)

  enc1_kernel<<<NBLK, 128, 0, stream>>>(atom, tvec, mvec, atom_emb, mag_w, mag_b,
      pos_w, pos_b, reduce_w, reduce_b, net_w1, net_b1, net_w2, net_b2,
      final_w, final_b, xf, pg);
  reduce_kernel<<<1, 1024, 0, stream>>>(pg, NBLK, gv);
  wprep_kernel<<<768, 256, 0, stream>>>(gru_wih, gru_whh, w16i, w16h);
  enc2_kernel<<<NBLK, 128, 0, stream>>>(xf, gv, redg_w, redg_b, wg_w1, wg_b1,
      wg_w2, wg_b2, gfinal_w, gfinal_b, pz);
  reduce_kernel<<<1, 1024, 0, stream>>>(pz, NBLK, oz);
  gru_kernel<<<1, 512, 0, stream>>>(w16i, gru_bih, gru_bhh, oz, enc);
  heads_kernel<<<NBLK, 128, 0, stream>>>(enc, ah_w1, ah_b1, ah_w2, ah_b2, ah_w, ah_b,
      ph_w1, ph_b1, ph_w2, ph_b2, ph_w, ph_b, mh_w1, mh_b1, mh_w2, mh_b2, mh_w, mh_b,
      oa, op, om);
}

// Round 8
// 112197.705 us; speedup vs baseline: 3.7827x; 1.1767x over previous
//
#include <hip/hip_runtime.h>
#include <hip/hip_bf16.h>

#define NEVT 32768
#define NBLK (NEVT / 8)

typedef _Float16 f16;
typedef _Float16 f16x2 __attribute__((ext_vector_type(2)));
typedef float f32x16 __attribute__((ext_vector_type(16)));
typedef float Row128[128];

#ifndef __has_builtin
#define __has_builtin(x) 0
#endif

__device__ __forceinline__ float dot2f(f16x2 a, f16x2 b, float c) {
#if __has_builtin(__builtin_amdgcn_fdot2)
  return __builtin_amdgcn_fdot2(a, b, c, false);
#else
  return c + (float)a[0] * (float)b[0] + (float)a[1] * (float)b[1];
#endif
}

__device__ __forceinline__ float lrelu(float v) { return v >= 0.f ? v : 0.2f * v; }

__device__ __forceinline__ float sigmoidf(float x) {
  return 1.f / (1.f + __expf(-x));
}

__device__ __forceinline__ float tanh_f(float x) {
  float ax = fabsf(x);
  float e = __expf(-2.f * ax);
  float t = (1.f - e) / (1.f + e);
  return x >= 0.f ? t : -t;
}

// One residual block on an 8-row tile held in LDS. 128 threads, thread u owns
// output unit u. Two internal barriers.
__device__ __forceinline__ void res_block(Row128* xb, Row128* hb,
    const float* __restrict__ w1, const float* __restrict__ b1,
    const float* __restrict__ w2, const float* __restrict__ b2, int u) {
  float acc[8];
  float bb = b1[u];
  #pragma unroll
  for (int r = 0; r < 8; ++r) acc[r] = bb;
  #pragma unroll 4
  for (int k = 0; k < 128; ++k) {
    float w = w1[u * 128 + k];
    #pragma unroll
    for (int r = 0; r < 8; ++r) acc[r] += w * xb[r][k];
  }
  #pragma unroll
  for (int r = 0; r < 8; ++r) hb[r][u] = lrelu(acc[r]);
  __syncthreads();
  bb = b2[u];
  #pragma unroll
  for (int r = 0; r < 8; ++r) acc[r] = bb;
  #pragma unroll 4
  for (int k = 0; k < 128; ++k) {
    float w = w2[u * 128 + k];
    #pragma unroll
    for (int r = 0; r < 8; ++r) acc[r] += w * hb[r][k];
  }
  #pragma unroll
  for (int r = 0; r < 8; ++r) xb[r][u] = lrelu(xb[r][u] + acc[r]);
  __syncthreads();
}

// ---------------- Encoder stage 1 ----------------
__global__ __launch_bounds__(128) void enc1_kernel(
    const int* __restrict__ atom, const float* __restrict__ tvec,
    const float* __restrict__ mvec, const float* __restrict__ atom_emb,
    const float* __restrict__ mag_w, const float* __restrict__ mag_b,
    const float* __restrict__ pos_w, const float* __restrict__ pos_b,
    const float* __restrict__ reduce_w, const float* __restrict__ reduce_b,
    const float* __restrict__ net_w1, const float* __restrict__ net_b1,
    const float* __restrict__ net_w2, const float* __restrict__ net_b2,
    const float* __restrict__ final_w, const float* __restrict__ final_b,
    float* __restrict__ xf, float* __restrict__ pg) {
  const int u = threadIdx.x;
  const int r0 = blockIdx.x * 8;
  __shared__ float xin[8][384];
  __shared__ float xb[8][128];
  __shared__ float hb[8][128];
  #pragma unroll
  for (int r = 0; r < 8; ++r) {
    int row = r0 + r;
    xin[r][u] = atom_emb[atom[row] * 128 + u];
    xin[r][128 + u] = tvec[row] * pos_w[u] + pos_b[u];
    xin[r][256 + u] = mvec[row] * mag_w[u] + mag_b[u];
  }
  __syncthreads();
  float acc[8];
  float bb = reduce_b[u];
  #pragma unroll
  for (int r = 0; r < 8; ++r) acc[r] = bb;
  #pragma unroll 4
  for (int k = 0; k < 384; ++k) {
    float w = reduce_w[u * 384 + k];
    #pragma unroll
    for (int r = 0; r < 8; ++r) acc[r] += w * xin[r][k];
  }
  #pragma unroll
  for (int r = 0; r < 8; ++r) xb[r][u] = acc[r];
  __syncthreads();
  for (int blk = 0; blk < 4; ++blk)
    res_block(xb, hb, net_w1 + blk * 16384, net_b1 + blk * 128,
              net_w2 + blk * 16384, net_b2 + blk * 128, u);
  bb = final_b[u];
  #pragma unroll
  for (int r = 0; r < 8; ++r) acc[r] = bb;
  #pragma unroll 4
  for (int k = 0; k < 128; ++k) {
    float w = final_w[u * 128 + k];
    #pragma unroll
    for (int r = 0; r < 8; ++r) acc[r] += w * xb[r][k];
  }
  float s = 0.f;
  #pragma unroll
  for (int r = 0; r < 8; ++r) {
    xf[(r0 + r) * 128 + u] = acc[r];
    s += acc[r];
  }
  pg[blockIdx.x * 128 + u] = s;
}

// ---------------- Deterministic column reduction: sum m rows of [128] -------
__global__ __launch_bounds__(1024) void reduce_kernel(
    const float* __restrict__ src, int m, float* __restrict__ dst) {
  int u = threadIdx.x & 127, c = threadIdx.x >> 7;
  float s = 0.f;
  for (int i = c; i < m; i += 8) s += src[i * 128 + u];
  __shared__ float tmp[8][128];
  tmp[c][u] = s;
  __syncthreads();
  if (c == 0) {
    float t = 0.f;
    #pragma unroll
    for (int j = 0; j < 8; ++j) t += tmp[j][u];
    dst[u] = t;
  }
}

// ---------------- Encoder stage 2 ----------------
__global__ __launch_bounds__(128) void enc2_kernel(
    const float* __restrict__ xf, const float* __restrict__ g,
    const float* __restrict__ redg_w, const float* __restrict__ redg_b,
    const float* __restrict__ wg_w1, const float* __restrict__ wg_b1,
    const float* __restrict__ wg_w2, const float* __restrict__ wg_b2,
    const float* __restrict__ gfinal_w, const float* __restrict__ gfinal_b,
    float* __restrict__ pz) {
  const int u = threadIdx.x;
  const int r0 = blockIdx.x * 8;
  __shared__ float xin[8][256];
  __shared__ float xb[8][128];
  __shared__ float hb[8][128];
  #pragma unroll
  for (int r = 0; r < 8; ++r) {
    xin[r][u] = xf[(r0 + r) * 128 + u];
    xin[r][128 + u] = g[u];
  }
  __syncthreads();
  float acc[8];
  float bb = redg_b[u];
  #pragma unroll
  for (int r = 0; r < 8; ++r) acc[r] = bb;
  #pragma unroll 4
  for (int k = 0; k < 256; ++k) {
    float w = redg_w[u * 256 + k];
    #pragma unroll
    for (int r = 0; r < 8; ++r) acc[r] += w * xin[r][k];
  }
  #pragma unroll
  for (int r = 0; r < 8; ++r) xb[r][u] = acc[r];
  __syncthreads();
  for (int blk = 0; blk < 4; ++blk)
    res_block(xb, hb, wg_w1 + blk * 16384, wg_b1 + blk * 128,
              wg_w2 + blk * 16384, wg_b2 + blk * 128, u);
  bb = gfinal_b[u];
  #pragma unroll
  for (int r = 0; r < 8; ++r) acc[r] = bb;
  #pragma unroll 4
  for (int k = 0; k < 128; ++k) {
    float w = gfinal_w[u * 128 + k];
    #pragma unroll
    for (int r = 0; r < 8; ++r) acc[r] += w * xb[r][k];
  }
  float s = 0.f;
  #pragma unroll
  for (int r = 0; r < 8; ++r) s += acc[r];
  pz[blockIdx.x * 128 + u] = s;
}

// ---------------- Weight pre-conversion f32 -> f16 ----------------
__global__ __launch_bounds__(256) void wprep_kernel(
    const float* __restrict__ wih, const float* __restrict__ whh,
    f16* __restrict__ w16i, f16* __restrict__ w16h) {
  int idx = blockIdx.x * 256 + threadIdx.x;
  if (idx < 196608) {
    w16i[idx] = (f16)wih[idx];
    w16h[idx] = (f16)whh[idx];
  }
}

// ---------------- Sequential GRU decoder (single workgroup, 1024 threads) ---
// R11: baseline structure + LDS as a PARALLEL feed pipe. Eight-round ledger:
// the only configuration that achieves the full ~102 B/cyc L2 stream rate is
// this baseline (1024 thr, 4 waves/SIMD, compiler-sunk weight loads, VGPR~52,
// 7700 cyc/step for 768 KB). Residency schemes all failed: arch-VGPR anchors
// spill (R4-R6), physical AGPRs collide with compiler spill slots (R7 NaN),
// class-"a" AGPRs work but add ~4500 cyc/step of v_accvgpr_read + exposed
// latency at 2 waves/SIMD (R10), fp8 decode is VALU-bound (R8), cross-CU
// handshakes ride the slow coherence fabric (R9).
// The untouched lever: the DS pipe is idle. ds_read_b128 (~85 B/cyc/CU) runs
// in PARALLEL with the L2 load path (~102 B/cyc). Unit J1 (used half in
// phase 0, half in phase 1) moves to LDS (128 KB, R6's proven conflict-free
// [chunk][tid] float4 layout - 2-way bank aliasing is free). Phases 0/1
// become 128 KB global + 64 KB LDS (LDS time hides under the global stream);
// phases 2/3 unchanged. Step model: 2x1250 + 2x1880 ~= 6300 cyc vs 7700.
// Everything else is byte-identical to the measured-106ms baseline.

#define PW(WV, K) __builtin_bit_cast(f16x2, (WV)[(K)])

#define DGRP(WV, G, Q) \
  a0_ = dot2f(PW(WV, 4*(G)+0), __builtin_bit_cast(f16x2, (Q).x), a0_); \
  a1_ = dot2f(PW(WV, 4*(G)+1), __builtin_bit_cast(f16x2, (Q).y), a1_); \
  a2_ = dot2f(PW(WV, 4*(G)+2), __builtin_bit_cast(f16x2, (Q).z), a2_); \
  a3_ = dot2f(PW(WV, 4*(G)+3), __builtin_bit_cast(f16x2, (Q).w), a3_);

#define DGRPQ(WQ, Q) \
  a0_ = dot2f(__builtin_bit_cast(f16x2,(WQ).x), __builtin_bit_cast(f16x2,(Q).x), a0_); \
  a1_ = dot2f(__builtin_bit_cast(f16x2,(WQ).y), __builtin_bit_cast(f16x2,(Q).y), a1_); \
  a2_ = dot2f(__builtin_bit_cast(f16x2,(WQ).z), __builtin_bit_cast(f16x2,(Q).z), a2_); \
  a3_ = dot2f(__builtin_bit_cast(f16x2,(WQ).w), __builtin_bit_cast(f16x2,(Q).w), a3_);

#define UNIT_DOT(WA, WB, SRC, DST, BIAS) do { \
  const float4* s4_ = (const float4*)(SRC); \
  float4 q0_ = s4_[0], q1_ = s4_[1], q2_ = s4_[2], q3_ = s4_[3]; \
  float4 q4_ = s4_[4], q5_ = s4_[5], q6_ = s4_[6], q7_ = s4_[7]; \
  float a0_ = (BIAS), a1_ = 0.f, a2_ = 0.f, a3_ = 0.f; \
  DGRP(WA, 0, q0_) DGRP(WA, 1, q1_) DGRP(WA, 2, q2_) DGRP(WA, 3, q3_) \
  DGRP(WB, 0, q4_) DGRP(WB, 1, q5_) DGRP(WB, 2, q6_) DGRP(WB, 3, q7_) \
  *(DST) = (a0_ + a1_) + (a2_ + a3_); \
} while (0)

// J1 unit from LDS: chunk c of thread t at float4 index c*1024 + t.
// Lane-contiguous ds_read_b128 (64 lanes x 16 B = 1024 B = 2-way aliasing,
// free per m136).
#define UNIT_DOT_L1() do { \
  const float4* s4_ = (const float4*)(usrc1); \
  float4 q0_ = s4_[0], q1_ = s4_[1], q2_ = s4_[2], q3_ = s4_[3]; \
  float4 q4_ = s4_[4], q5_ = s4_[5], q6_ = s4_[6], q7_ = s4_[7]; \
  float a0_ = ubias1, a1_ = 0.f, a2_ = 0.f, a3_ = 0.f; \
  float4 w_; \
  w_ = wlds1[0*1024 + tid]; DGRPQ(w_, q0_) \
  w_ = wlds1[1*1024 + tid]; DGRPQ(w_, q1_) \
  w_ = wlds1[2*1024 + tid]; DGRPQ(w_, q2_) \
  w_ = wlds1[3*1024 + tid]; DGRPQ(w_, q3_) \
  w_ = wlds1[4*1024 + tid]; DGRPQ(w_, q4_) \
  w_ = wlds1[5*1024 + tid]; DGRPQ(w_, q5_) \
  w_ = wlds1[6*1024 + tid]; DGRPQ(w_, q6_) \
  w_ = wlds1[7*1024 + tid]; DGRPQ(w_, q7_) \
  *udst1 = (a0_ + a1_) + (a2_ + a3_); \
} while (0)

#define F32T(WV, K, XS, OFF) { f16x2 p_ = PW(WV, (K)); \
  a0_ += (float)p_[0] * (XS)[(OFF) + 2*(K)]; \
  a1_ += (float)p_[1] * (XS)[(OFF) + 2*(K) + 1]; }

#define UNIT_DOT_F32(WA, WB, XS, DST, BIAS) do { \
  float a0_ = (BIAS), a1_ = 0.f; \
  F32T(WA,0,XS,0) F32T(WA,1,XS,0) F32T(WA,2,XS,0) F32T(WA,3,XS,0) \
  F32T(WA,4,XS,0) F32T(WA,5,XS,0) F32T(WA,6,XS,0) F32T(WA,7,XS,0) \
  F32T(WA,8,XS,0) F32T(WA,9,XS,0) F32T(WA,10,XS,0) F32T(WA,11,XS,0) \
  F32T(WA,12,XS,0) F32T(WA,13,XS,0) F32T(WA,14,XS,0) F32T(WA,15,XS,0) \
  F32T(WB,0,XS,32) F32T(WB,1,XS,32) F32T(WB,2,XS,32) F32T(WB,3,XS,32) \
  F32T(WB,4,XS,32) F32T(WB,5,XS,32) F32T(WB,6,XS,32) F32T(WB,7,XS,32) \
  F32T(WB,8,XS,32) F32T(WB,9,XS,32) F32T(WB,10,XS,32) F32T(WB,11,XS,32) \
  F32T(WB,12,XS,32) F32T(WB,13,XS,32) F32T(WB,14,XS,32) F32T(WB,15,XS,32) \
  *(DST) = a0_ + a1_; \
} while (0)

#define L4(WV, I, Q) \
  (WV)[4*(I)+0] = (Q).x; (WV)[4*(I)+1] = (Q).y; \
  (WV)[4*(I)+2] = (Q).z; (WV)[4*(I)+3] = (Q).w;

#define LOAD_W16(WA, WB, BASE) do { \
  const float4* p_ = (const float4*)(BASE); \
  float4 q0_ = p_[0], q1_ = p_[1], q2_ = p_[2], q3_ = p_[3]; \
  float4 q4_ = p_[4], q5_ = p_[5], q6_ = p_[6], q7_ = p_[7]; \
  L4(WA, 0, q0_) L4(WA, 1, q1_) L4(WA, 2, q2_) L4(WA, 3, q3_) \
  L4(WB, 0, q4_) L4(WB, 1, q5_) L4(WB, 2, q6_) L4(WB, 3, q7_) \
} while (0)

#define SETUP_UNIT(J, JJ, P) \
  { int u_ = tid + (JJ)*1024; int lin_ = u_ / 1536; int w_ = u_ % 1536; \
    int layer_ = 2*(P) + lin_; int side_ = w_ / 768; int v_ = w_ % 768; \
    int row_ = v_ >> 1; int half_ = v_ & 1; \
    const f16* ws_ = side_ ? w16h : w16i; \
    const float* bs_ = side_ ? bhh : bih; \
    wb##J = ws_ + (size_t)(layer_*384 + row_)*128 + half_*64; \
    ubias##J = (half_ == 0) ? bs_[layer_*384 + row_] : 0.f; \
    usrc##J = (const f16x2*)(side_ ? &h16[layer_][0] : &cur16[0]) + half_*32; \
    udst##J = (side_ ? pgh : pgi) + v_; }

#define GATE(L, T) \
  if (tid < 128) { \
    const float2* gi2_ = (const float2*)pgi; const float2* gh2_ = (const float2*)pgh; \
    float2 ar_ = gi2_[tid],      br_ = gh2_[tid]; \
    float2 az_ = gi2_[128+tid],  bz_ = gh2_[128+tid]; \
    float2 an_ = gi2_[256+tid],  bn_ = gh2_[256+tid]; \
    float r_ = sigmoidf((ar_.x + ar_.y) + (br_.x + br_.y)); \
    float z_ = sigmoidf((az_.x + az_.y) + (bz_.x + bz_.y)); \
    float n_ = tanh_f((an_.x + an_.y) + r_ * (bn_.x + bn_.y)); \
    float h_ = (1.f - z_) * n_ + z_ * h32[L][tid]; \
    h32[L][tid] = h_; f16 hh_ = (f16)h_; \
    h16[L][tid] = hh_; cur16[tid] = hh_; \
    if ((L) == 3) enc[(size_t)(T) * 128 + tid] = h_; \
  }

__global__ __attribute__((amdgpu_flat_work_group_size(1024, 1024)))
__attribute__((amdgpu_waves_per_eu(4, 4))) void gru_kernel(
    const f16* __restrict__ w16i, const f16* __restrict__ w16h,
    const float* __restrict__ bih, const float* __restrict__ bhh,
    const float* __restrict__ zvec, float* __restrict__ enc) {
  const int tid = threadIdx.x;

  __shared__ __align__(16) float4 wlds1[8192];   // 128 KB: J1 weights
  __shared__ __align__(16) float pgi[768];
  __shared__ __align__(16) float pgh[768];
  __shared__ __align__(16) f16 cur16[128];
  __shared__ __align__(16) f16 h16[4][128];
  __shared__ __align__(16) float h32[4][128];
  __shared__ __align__(16) float cur32[128];

  const f16* wb0; const f16x2* usrc0; float* udst0; float ubias0;
  const f16* wb1; const f16x2* usrc1; float* udst1; float ubias1;
  const f16* wb2; const f16x2* usrc2; float* udst2; float ubias2;
  const f16* wb3; const f16x2* usrc3; float* udst3; float ubias3;
  const f16* wb4; const f16x2* usrc4; float* udst4; float ubias4;
  const f16* wb5; const f16x2* usrc5; float* udst5; float ubias5;

  SETUP_UNIT(0, 0, 0) SETUP_UNIT(1, 1, 0) SETUP_UNIT(2, 2, 0)
  SETUP_UNIT(3, 0, 1) SETUP_UNIT(4, 1, 1) SETUP_UNIT(5, 2, 1)

  f32x16 w0a, w0b, w2a, w2b, w3a, w3b, w4a, w4b, w5a, w5b;
  LOAD_W16(w0a, w0b, wb0); LOAD_W16(w2a, w2b, wb2);
  LOAD_W16(w3a, w3b, wb3); LOAD_W16(w4a, w4b, wb4); LOAD_W16(w5a, w5b, wb5);

  // J1 weights -> LDS, [chunk][tid] so each wave's ds_read_b128 is
  // lane-contiguous (2-way bank aliasing only, which is free).
  {
    const float4* p1 = (const float4*)wb1;
    #pragma unroll
    for (int c = 0; c < 8; ++c) wlds1[c * 1024 + tid] = p1[c];
  }

  if (tid < 128) {
    cur32[tid] = zvec[tid];
    cur16[tid] = (f16)0.f;
    #pragma unroll
    for (int l = 0; l < 4; ++l) { h32[l][tid] = 0.f; h16[l][tid] = (f16)0.f; }
  }
  __syncthreads();

  // ---- peeled step t = 0 (layer-0 gi uses f32 z; h == 0 elsewhere) ----
  {
    if (tid < 768) { UNIT_DOT_F32(w0a, w0b, cur32 + (tid & 1) * 64, udst0, ubias0); }
    else           { UNIT_DOT(w0a, w0b, usrc0, udst0, ubias0); }
    if (tid < 512) UNIT_DOT_L1();
    __syncthreads();
    GATE(0, 0)
    __syncthreads();
    if (tid >= 512) UNIT_DOT_L1();
    UNIT_DOT(w2a, w2b, usrc2, udst2, ubias2);
    __syncthreads();
    GATE(1, 0)
    __syncthreads();
    UNIT_DOT(w3a, w3b, usrc3, udst3, ubias3);
    if (tid < 512) UNIT_DOT(w4a, w4b, usrc4, udst4, ubias4);
    __syncthreads();
    GATE(2, 0)
    __syncthreads();
    if (tid >= 512) UNIT_DOT(w4a, w4b, usrc4, udst4, ubias4);
    UNIT_DOT(w5a, w5b, usrc5, udst5, ubias5);
    __syncthreads();
    GATE(3, 0)
    __syncthreads();
  }

  #pragma unroll 1
  for (int t = 1; t < NEVT; ++t) {
    // ---- phase 0 (layer 0): J0 streamed + J1-half from LDS ----
    UNIT_DOT(w0a, w0b, usrc0, udst0, ubias0);
    if (tid < 512) UNIT_DOT_L1();
    __syncthreads();
    GATE(0, t)
    __syncthreads();
    // ---- phase 1 (layer 1): J1-half from LDS + J2 streamed ----
    if (tid >= 512) UNIT_DOT_L1();
    UNIT_DOT(w2a, w2b, usrc2, udst2, ubias2);
    __syncthreads();
    GATE(1, t)
    __syncthreads();
    // ---- phase 2 (layer 2): J3 + J4-half streamed ----
    UNIT_DOT(w3a, w3b, usrc3, udst3, ubias3);
    if (tid < 512) UNIT_DOT(w4a, w4b, usrc4, udst4, ubias4);
    __syncthreads();
    GATE(2, t)
    __syncthreads();
    // ---- phase 3 (layer 3): J4-half + J5 streamed ----
    if (tid >= 512) UNIT_DOT(w4a, w4b, usrc4, udst4, ubias4);
    UNIT_DOT(w5a, w5b, usrc5, udst5, ubias5);
    __syncthreads();
    GATE(3, t)
    __syncthreads();
  }
}

// ---------------- Output heads ----------------
__global__ __launch_bounds__(128) void heads_kernel(
    const float* __restrict__ enc,
    const float* __restrict__ ah_w1, const float* __restrict__ ah_b1,
    const float* __restrict__ ah_w2, const float* __restrict__ ah_b2,
    const float* __restrict__ ah_w, const float* __restrict__ ah_b,
    const float* __restrict__ ph_w1, const float* __restrict__ ph_b1,
    const float* __restrict__ ph_w2, const float* __restrict__ ph_b2,
    const float* __restrict__ ph_w, const float* __restrict__ ph_b,
    const float* __restrict__ mh_w1, const float* __restrict__ mh_b1,
    const float* __restrict__ mh_w2, const float* __restrict__ mh_b2,
    const float* __restrict__ mh_w, const float* __restrict__ mh_b,
    float* __restrict__ oa, float* __restrict__ op, float* __restrict__ om) {
  const int u = threadIdx.x;
  const int r0 = blockIdx.x * 8;
  __shared__ float eb[8][128], xb[8][128], hb[8][128];
  #pragma unroll
  for (int r = 0; r < 8; ++r) eb[r][u] = enc[(size_t)(r0 + r) * 128 + u];
  // ---- atoms head ----
  #pragma unroll
  for (int r = 0; r < 8; ++r) xb[r][u] = eb[r][u];
  __syncthreads();
  for (int blk = 0; blk < 2; ++blk)
    res_block(xb, hb, ah_w1 + blk * 16384, ah_b1 + blk * 128,
              ah_w2 + blk * 16384, ah_b2 + blk * 128, u);
  {
    float acc[8];
    float bb = ah_b[u];
    #pragma unroll
    for (int r = 0; r < 8; ++r) acc[r] = bb;
    #pragma unroll 4
    for (int k = 0; k < 128; ++k) {
      float w = ah_w[u * 128 + k];
      #pragma unroll
      for (int r = 0; r < 8; ++r) acc[r] += w * xb[r][k];
    }
    #pragma unroll
    for (int r = 0; r < 8; ++r) oa[(size_t)(r0 + r) * 128 + u] = acc[r];
  }
  __syncthreads();
  // ---- pos head ----
  #pragma unroll
  for (int r = 0; r < 8; ++r) xb[r][u] = eb[r][u];
  __syncthreads();
  for (int blk = 0; blk < 2; ++blk)
    res_block(xb, hb, ph_w1 + blk * 16384, ph_b1 + blk * 128,
              ph_w2 + blk * 16384, ph_b2 + blk * 128, u);
  if (u < 8) {
    int r = u;
    float s = ph_b[0];
    for (int k = 0; k < 128; ++k) s += ph_w[k] * xb[r][k];
    s = s < 0.f ? 0.f : (s > 1.f ? 1.f : s);
    op[r0 + r] = s;
  }
  __syncthreads();
  // ---- mags head ----
  #pragma unroll
  for (int r = 0; r < 8; ++r) xb[r][u] = eb[r][u];
  __syncthreads();
  for (int blk = 0; blk < 2; ++blk)
    res_block(xb, hb, mh_w1 + blk * 16384, mh_b1 + blk * 128,
              mh_w2 + blk * 16384, mh_b2 + blk * 128, u);
  if (u < 8) {
    int r = u;
    float s = mh_b[0];
    for (int k = 0; k < 128; ++k) s += mh_w[k] * xb[r][k];
    om[r0 + r] = s;
  }
}

extern "C" void kernel_launch(void* const* d_in, const int* in_sizes, int n_in,
                              void* d_out, int out_size, void* d_ws, size_t ws_size,
                              hipStream_t stream) {
  const int* atom = (const int*)d_in[0];
  const float* tvec = (const float*)d_in[1];
  const float* mvec = (const float*)d_in[2];
  const float* atom_emb = (const float*)d_in[3];
  const float* mag_w = (const float*)d_in[4];
  const float* mag_b = (const float*)d_in[5];
  const float* pos_w = (const float*)d_in[6];
  const float* pos_b = (const float*)d_in[7];
  const float* reduce_w = (const float*)d_in[8];
  const float* reduce_b = (const float*)d_in[9];
  const float* net_w1 = (const float*)d_in[10];
  const float* net_b1 = (const float*)d_in[11];
  const float* net_w2 = (const float*)d_in[12];
  const float* net_b2 = (const float*)d_in[13];
  const float* final_w = (const float*)d_in[14];
  const float* final_b = (const float*)d_in[15];
  const float* redg_w = (const float*)d_in[16];
  const float* redg_b = (const float*)d_in[17];
  const float* wg_w1 = (const float*)d_in[18];
  const float* wg_b1 = (const float*)d_in[19];
  const float* wg_w2 = (const float*)d_in[20];
  const float* wg_b2 = (const float*)d_in[21];
  const float* gfinal_w = (const float*)d_in[22];
  const float* gfinal_b = (const float*)d_in[23];
  const float* gru_wih = (const float*)d_in[24];
  const float* gru_whh = (const float*)d_in[25];
  const float* gru_bih = (const float*)d_in[26];
  const float* gru_bhh = (const float*)d_in[27];
  const float* ah_w1 = (const float*)d_in[28];
  const float* ah_b1 = (const float*)d_in[29];
  const float* ah_w2 = (const float*)d_in[30];
  const float* ah_b2 = (const float*)d_in[31];
  const float* ah_w = (const float*)d_in[32];
  const float* ah_b = (const float*)d_in[33];
  const float* ph_w1 = (const float*)d_in[34];
  const float* ph_b1 = (const float*)d_in[35];
  const float* ph_w2 = (const float*)d_in[36];
  const float* ph_b2 = (const float*)d_in[37];
  const float* ph_w = (const float*)d_in[38];
  const float* ph_b = (const float*)d_in[39];
  const float* mh_w1 = (const float*)d_in[40];
  const float* mh_b1 = (const float*)d_in[41];
  const float* mh_w2 = (const float*)d_in[42];
  const float* mh_b2 = (const float*)d_in[43];
  const float* mh_w = (const float*)d_in[44];
  const float* mh_b = (const float*)d_in[45];

  float* out = (float*)d_out;
  float* oa = out;                        // atoms [N,128]
  float* op = out + (size_t)NEVT * 128;   // pos [N]
  float* om = op + NEVT;                  // mags [N]
  float* oz = om + NEVT;                  // z [128]

  float* enc = (float*)d_ws;              // encodings [N,128] : 16 MB
  float* pg = enc + (size_t)NEVT * 128;   // stage-1 partials: 2 MB (reused for w16)
  float* pz = pg + (size_t)NBLK * 128;    // stage-2 partials: 2 MB
  float* gv = pz + (size_t)NBLK * 128;    // g [128]
  float* xf = oa;  // stage-1 output staged in atoms region; heads overwrite later

  // f16 weight copies overlay the pg region once pg has been reduced into gv.
  f16* w16i = (f16*)pg;                   // 384 KB
  f16* w16h = w16i + 196608;              // 384 KB

  enc1_kernel<<<NBLK, 128, 0, stream>>>(atom, tvec, mvec, atom_emb, mag_w, mag_b,
      pos_w, pos_b, reduce_w, reduce_b, net_w1, net_b1, net_w2, net_b2,
      final_w, final_b, xf, pg);
  reduce_kernel<<<1, 1024, 0, stream>>>(pg, NBLK, gv);
  wprep_kernel<<<768, 256, 0, stream>>>(gru_wih, gru_whh, w16i, w16h);
  enc2_kernel<<<NBLK, 128, 0, stream>>>(xf, gv, redg_w, redg_b, wg_w1, wg_b1,
      wg_w2, wg_b2, gfinal_w, gfinal_b, pz);
  reduce_kernel<<<1, 1024, 0, stream>>>(pz, NBLK, oz);
  gru_kernel<<<1, 1024, 0, stream>>>(w16i, w16h, gru_bih, gru_bhh, oz, enc);
  heads_kernel<<<NBLK, 128, 0, stream>>>(enc, ah_w1, ah_b1, ah_w2, ah_b2, ah_w, ah_b,
      ph_w1, ph_b1, ph_w2, ph_b2, ph_w, ph_b, mh_w1, mh_b1, mh_w2, mh_b2, mh_w, mh_b,
      oa, op, om);
}